// Round 16
// baseline (856.538 us; speedup 1.0000x reference)
//
#include <hip/hip_runtime.h>
#include <stdint.h>

// ---- problem constants (B=4, H=W=224, C=192, heads=6, win=7, shift=3) ----
#define MB    50176         // tokens per batch image (224*224)
#define CDIM  192

typedef __attribute__((ext_vector_type(8))) short bf16x8;   // MFMA A/B frag (4 VGPR)
typedef __attribute__((ext_vector_type(4))) float f32x4;    // MFMA C/D frag

#define WFENCE do{ asm volatile("s_waitcnt lgkmcnt(0)" ::: "memory"); \
                   __builtin_amdgcn_sched_barrier(0); }while(0)

__device__ __forceinline__ float wsum(float v){
  #pragma unroll
  for (int m=32;m>=1;m>>=1) v += __shfl_xor(v,m,64);
  return v;
}
__device__ __forceinline__ float bfbits2f(uint32_t h){
  union{uint32_t u; float f;} x; x.u = h<<16; return x.f;
}
__device__ __forceinline__ uint16_t f2bfbits(float f){
  union{float ff; uint32_t u;} x; x.ff = f;
  return (uint16_t)((x.u + 0x7FFFu + ((x.u>>16)&1u)) >> 16);
}
__device__ __forceinline__ void gload16(const void* g, void* l){
  __builtin_amdgcn_global_load_lds(
      (const __attribute__((address_space(1))) uint32_t*)g,
      (__attribute__((address_space(3))) uint32_t*)l, 16, 0, 0);
}
// fast gelu: x * sigmoid(1.59576912x + 0.07135481x^3)  (tanh-form, |err|<=3e-4)
__device__ __forceinline__ float fast_gelu(float v){
  float z = v*(1.5957691f + 0.07135481f*v*v);
  return v * __builtin_amdgcn_rcpf(1.f + __expf(-z));
}
// window-order global row -> global token index (roll-back + window-reverse)
__device__ __forceinline__ size_t row2tok(int r_g){
  int widx = r_g/49, tpos = r_g - widx*49;
  int b = widx>>10, rem = widx&1023;
  int h = (rem>>5)*7 + tpos/7 + 3; if (h>=224) h-=224;
  int w = (rem&31)*7 + (tpos - (tpos/7)*7) + 3; if (w>=224) w-=224;
  return (size_t)b*MB + (size_t)h*224 + w;
}

// ---------------- prep: all weight converts (f32 KxN -> bf16 NxK) + btbl ---
__global__ __launch_bounds__(256) void prep_kernel(
    const float* __restrict__ qkv_w, const float* __restrict__ proj_w,
    const float* __restrict__ fc1_w, const float* __restrict__ fc2_w,
    const float* __restrict__ rpb,
    uint16_t* __restrict__ qkvW, uint16_t* __restrict__ prjW,
    uint16_t* __restrict__ fc1W, uint16_t* __restrict__ fc2W,
    float* __restrict__ btbl){
  int idx = blockIdx.x*256 + threadIdx.x;
  if (idx < 110592){ int k=idx/576, n=idx-k*576; qkvW[n*192+k]=f2bfbits(qkv_w[idx]); return; }
  idx -= 110592;
  if (idx < 36864){ int k=idx/192, n=idx-k*192; prjW[n*192+k]=f2bfbits(proj_w[idx]); return; }
  idx -= 36864;
  if (idx < 147456){ int k=idx/768, n=idx-k*768; fc1W[n*192+k]=f2bfbits(fc1_w[idx]); return; }
  idx -= 147456;
  if (idx < 147456){ int k=idx/192, n=idx-k*192; fc2W[n*768+k]=f2bfbits(fc2_w[idx]); return; }
  idx -= 147456;
  if (idx >= 98304) return;
  int j = idx & 63, i = (idx>>6) & 63;
  int hd = (idx>>12) % 6, cls = (idx>>12)/6;
  float v = -1e9f;
  if (i < 49 && j < 49){
    int dh = i/7 - j/7, dw = i%7 - j%7;
    v = rpb[((dh+6)*13 + (dw+6))*6 + hd];
    int cH = cls>>1, cW = cls&1;
    int li = (cH ? (i/7 < 4 ? 1 : 2) : 0)*3 + (cW ? (i%7 < 4 ? 1 : 2) : 0);
    int lj = (cH ? (j/7 < 4 ? 1 : 2) : 0)*3 + (cW ? (j%7 < 4 ? 1 : 2) : 0);
    if (li != lj) v = -1e9f;
  }
  btbl[idx] = v;
}

// ---------------- LN1 + roll + window-partition gather -> bf16 -------------
__global__ __launch_bounds__(256) void ln1_kernel(
    const float* __restrict__ x, const float* __restrict__ g,
    const float* __restrict__ bt, uint16_t* __restrict__ dst, int row0){
  int wid_l = (int)((blockIdx.x*256u + threadIdx.x) >> 6);
  int lane  = threadIdx.x & 63;
  size_t sidx = row2tok(row0 + wid_l);
  const float* s = x + sidx*CDIM;
  float v0=s[lane], v1=s[lane+64], v2=s[lane+128];
  float mu  = wsum(v0+v1+v2) * (1.f/192.f);
  float var = wsum(v0*v0+v1*v1+v2*v2)*(1.f/192.f) - mu*mu;
  float rs  = rsqrtf(var + 1e-5f);
  uint16_t* d = dst + (size_t)wid_l*CDIM;
  d[lane]     = f2bfbits((v0-mu)*rs*g[lane]     + bt[lane]);
  d[lane+64]  = f2bfbits((v1-mu)*rs*g[lane+64]  + bt[lane+64]);
  d[lane+128] = f2bfbits((v2-mu)*rs*g[lane+128] + bt[lane+128]);
}

// ------- qkv MFMA GEMM (r13 form): 128x64 tile, 4 waves, 2-phase dbuf ------
__global__ __launch_bounds__(256) void qkv_gemm(
    const uint16_t* __restrict__ A, const uint16_t* __restrict__ WT,
    const float* __restrict__ bias, uint16_t* __restrict__ outp){
  __shared__ __attribute__((aligned(16))) char As[2][128*128];
  __shared__ __attribute__((aligned(16))) char Bs[2][64*128];
  const int tid  = threadIdx.x;
  const int lane = tid & 63;
  const int wid  = tid >> 6;
  const int brow = blockIdx.y * 128;
  const int bcol = blockIdx.x * 64;

  f32x4 acc[4][2];
  #pragma unroll
  for (int m=0;m<4;m++)
    #pragma unroll
    for (int n=0;n<2;n++) acc[m][n] = (f32x4){0.f,0.f,0.f,0.f};

  const int srow = lane >> 3;
  const int sg   = (lane & 7) ^ srow;
  const int wm = wid >> 1, wn = wid & 1;
  const int lrow16 = lane & 15, lkh = lane >> 4;

  #define STAGE(k0, Ad, Bd) do{ \
    _Pragma("unroll") \
    for (int c = 0; c < 4; c++){ \
      int ch = wid*4 + c; \
      gload16(A + (size_t)(brow + ch*8 + srow)*192 + (k0) + sg*8, (Ad) + ch*1024); \
    } \
    _Pragma("unroll") \
    for (int c = 0; c < 2; c++){ \
      int ch = wid*2 + c; \
      gload16(WT + (size_t)(bcol + ch*8 + srow)*192 + (k0) + sg*8, (Bd) + ch*1024); \
    } \
  }while(0)

  STAGE(0, As[0], Bs[0]);
  #pragma unroll
  for (int ki = 0; ki < 3; ki++){
    const int cur = ki & 1;
    if (ki+1 < 3){
      STAGE((ki+1)*64, As[cur^1], Bs[cur^1]);
      asm volatile("s_waitcnt vmcnt(6)" ::: "memory");
    } else {
      asm volatile("s_waitcnt vmcnt(0)" ::: "memory");
    }
    __builtin_amdgcn_s_barrier();
    __builtin_amdgcn_sched_barrier(0);

    bf16x8 af[4][2], bfr[2][2];
    #pragma unroll
    for (int m=0;m<4;m++)
      #pragma unroll
      for (int ks=0;ks<2;ks++){
        int arow = wm*64 + m*16 + lrow16;
        af[m][ks] = *(const bf16x8*)(As[cur] + arow*128 + (((ks*4+lkh) ^ (arow&7))<<4));
      }
    #pragma unroll
    for (int n=0;n<2;n++)
      #pragma unroll
      for (int ks=0;ks<2;ks++){
        int brn = wn*32 + n*16 + lrow16;
        bfr[n][ks] = *(const bf16x8*)(Bs[cur] + brn*128 + (((ks*4+lkh) ^ (brn&7))<<4));
      }
    #pragma unroll
    for (int m=0;m<4;m++)
      #pragma unroll
      for (int n=0;n<2;n++)
        #pragma unroll
        for (int ks=0;ks<2;ks++)
          acc[m][n] = __builtin_amdgcn_mfma_f32_16x16x32_bf16(
              af[m][ks], bfr[n][ks], acc[m][n], 0, 0, 0);
    if (ki+1 < 3) __builtin_amdgcn_s_barrier();
  }
  #undef STAGE

  float bi[2];
  #pragma unroll
  for (int n=0;n<2;n++) bi[n] = bias[bcol + wn*32 + n*16 + lrow16];
  #pragma unroll
  for (int m=0;m<4;m++){
    #pragma unroll
    for (int j=0;j<4;j++){
      int r = brow + wm*64 + m*16 + lkh*4 + j;
      #pragma unroll
      for (int n=0;n<2;n++)
        outp[(size_t)r*576 + bcol + wn*32 + n*16 + lrow16] = f2bfbits(acc[m][n][j] + bi[n]);
    }
  }
}

// ----- proj GEMM (64x192 tile, 6 waves, wave 32x64) + fused LN2 ------------
__global__ __launch_bounds__(384) void proj_ln2(
    const uint16_t* __restrict__ A, const uint16_t* __restrict__ WT,
    const float* __restrict__ pbias, const float* __restrict__ x,
    const float* __restrict__ g2, const float* __restrict__ b2,
    uint16_t* __restrict__ x2out, uint16_t* __restrict__ ln2out, int row0){
  __shared__ __attribute__((aligned(16))) char As[64*128];    // [64][64k]
  __shared__ __attribute__((aligned(16))) char Bs[192*128];   // [192][64k]
  __shared__ float stats[3][64][2];
  __shared__ int tokt[64];
  const int tid  = threadIdx.x;
  const int lane = tid & 63;
  const int wid  = tid >> 6;          // 0..5
  const int pm = wid / 3, pn = wid - pm*3;
  const int brow = blockIdx.x * 64;
  const int srow = lane >> 3;
  const int sg   = (lane & 7) ^ srow;
  const int r16 = lane & 15, t4 = lane >> 4;

  if (tid < 64) tokt[tid] = (int)row2tok(row0 + brow + tid);

  f32x4 acc[2][4];
  #pragma unroll
  for (int m=0;m<2;m++)
    #pragma unroll
    for (int n=0;n<4;n++) acc[m][n] = (f32x4){0.f,0.f,0.f,0.f};

  for (int k0 = 0; k0 < 192; k0 += 64){
    for (int ch = wid; ch < 8; ch += 6)
      gload16(A + (size_t)(brow + ch*8 + srow)*192 + k0 + sg*8, As + ch*1024);
    for (int ch = wid; ch < 24; ch += 6)
      gload16(WT + (size_t)(ch*8 + srow)*192 + k0 + sg*8, Bs + ch*1024);
    __syncthreads();

    bf16x8 af[2][2], bfr[4][2];
    #pragma unroll
    for (int m=0;m<2;m++)
      #pragma unroll
      for (int ks=0;ks<2;ks++){
        int arow = pm*32 + m*16 + r16;
        af[m][ks] = *(const bf16x8*)(As + arow*128 + (((ks*4+t4) ^ (arow&7))<<4));
      }
    #pragma unroll
    for (int n=0;n<4;n++)
      #pragma unroll
      for (int ks=0;ks<2;ks++){
        int brn = pn*64 + n*16 + r16;
        bfr[n][ks] = *(const bf16x8*)(Bs + brn*128 + (((ks*4+t4) ^ (brn&7))<<4));
      }
    #pragma unroll
    for (int m=0;m<2;m++)
      #pragma unroll
      for (int n=0;n<4;n++)
        #pragma unroll
        for (int ks=0;ks<2;ks++)
          acc[m][n] = __builtin_amdgcn_mfma_f32_16x16x32_bf16(
              af[m][ks], bfr[n][ks], acc[m][n], 0, 0, 0);
    __syncthreads();
  }

  float bi[4], g2v[4], b2v[4];
  #pragma unroll
  for (int n=0;n<4;n++){
    int c = pn*64 + n*16 + r16;
    bi[n] = pbias[c]; g2v[n] = g2[c]; b2v[n] = b2[c];
  }
  #pragma unroll
  for (int m=0;m<2;m++){
    #pragma unroll
    for (int j=0;j<4;j++){
      int lr = pm*32 + m*16 + t4*4 + j;
      size_t pr = (size_t)tokt[lr]*CDIM;
      float s1 = 0.f, s2 = 0.f;
      #pragma unroll
      for (int n=0;n<4;n++){
        int c = pn*64 + n*16 + r16;
        float y = acc[m][n][j] + bi[n] + x[pr + c];
        acc[m][n][j] = y;
        x2out[pr + c] = f2bfbits(y);
        s1 += y; s2 = fmaf(y, y, s2);
      }
      #pragma unroll
      for (int mk=1; mk<16; mk<<=1){
        s1 += __shfl_xor(s1, mk, 64);
        s2 += __shfl_xor(s2, mk, 64);
      }
      if (r16 == 0){ stats[pn][lr][0] = s1; stats[pn][lr][1] = s2; }
    }
  }
  __syncthreads();
  #pragma unroll
  for (int m=0;m<2;m++){
    #pragma unroll
    for (int j=0;j<4;j++){
      int lr = pm*32 + m*16 + t4*4 + j;
      float s1 = stats[0][lr][0] + stats[1][lr][0] + stats[2][lr][0];
      float s2 = stats[0][lr][1] + stats[1][lr][1] + stats[2][lr][1];
      float mu = s1*(1.f/192.f);
      float rs = rsqrtf(s2*(1.f/192.f) - mu*mu + 1e-5f);
      size_t wr = (size_t)(brow + lr)*CDIM;
      #pragma unroll
      for (int n=0;n<4;n++){
        int c = pn*64 + n*16 + r16;
        ln2out[wr + c] = f2bfbits((acc[m][n][j]-mu)*rs*g2v[n] + b2v[n]);
      }
    }
  }
}

// ----- fused MLP: ln2out -> fc1 -> gelu -> fc2 -> +x2 -> out (LDS-routed) --
// 64 rows/block, 6 waves (2 row x 3 col panels). A-tile in LDS (staged once),
// W1/W2 B-frags streamed from L2-resident weights, hid chunk via padded LDS.
__global__ __launch_bounds__(384) void mlp_kernel(
    const uint16_t* __restrict__ A,      // ln2out, window order [T][192]
    const uint16_t* __restrict__ W1T,    // [768][192] bf16
    const uint16_t* __restrict__ W2T,    // [192][768] bf16
    const float* __restrict__ b1, const float* __restrict__ b2,
    const uint16_t* __restrict__ x2,     // x2 bf16, token order
    float* __restrict__ out, int row0){
  __shared__ __attribute__((aligned(16))) char As[3*8192];  // [3 kb][8 ch][1KB]
  __shared__ uint16_t hid[64][104];                         // pad: 2-way free
  __shared__ int tokt[64];
  const int tid  = threadIdx.x;
  const int lane = tid & 63, wid = tid >> 6;
  const int pm = wid / 3, pn = wid - pm*3;
  const int r16 = lane & 15, t4 = lane >> 4;
  const int brow = blockIdx.x * 64;
  const int srow = lane >> 3;
  const int sg   = (lane & 7) ^ srow;

  if (tid < 64) tokt[tid] = (int)row2tok(row0 + brow + tid);

  // stage A tile 64x192 once: 24 chunks of (8 rows x 8 granules)
  for (int idx = wid; idx < 24; idx += 6){
    int kb = idx >> 3, ch = idx & 7;
    gload16(A + (size_t)(brow + ch*8 + srow)*192 + kb*64 + sg*8,
            As + kb*8192 + ch*1024);
  }
  __syncthreads();   // drains vmcnt + lgkm

  f32x4 acc2[2][4];
  #pragma unroll
  for (int m=0;m<2;m++)
    #pragma unroll
    for (int n=0;n<4;n++) acc2[m][n] = (f32x4){0.f,0.f,0.f,0.f};

  #pragma unroll 1
  for (int hc = 0; hc < 8; hc++){
    // ---- fc1 partial: 64 rows x 96 hid cols; wave tile 32x32 ----
    f32x4 acc1[2][2];
    #pragma unroll
    for (int m=0;m<2;m++)
      #pragma unroll
      for (int n=0;n<2;n++) acc1[m][n] = (f32x4){0.f,0.f,0.f,0.f};
    #pragma unroll
    for (int kk=0;kk<6;kk++){
      bf16x8 bw[2];
      #pragma unroll
      for (int n=0;n<2;n++)
        bw[n] = *(const bf16x8*)(W1T + (size_t)(hc*96 + pn*32 + n*16 + r16)*192 + kk*32 + t4*8);
      bf16x8 af[2];
      #pragma unroll
      for (int m=0;m<2;m++){
        int arow = pm*32 + m*16 + r16;
        af[m] = *(const bf16x8*)(As + (kk>>1)*8192 + (arow>>3)*1024 + (arow&7)*128
                                 + ((((kk&1)*4 + t4) ^ (arow&7))<<4));
      }
      #pragma unroll
      for (int m=0;m<2;m++)
        #pragma unroll
        for (int n=0;n<2;n++)
          acc1[m][n] = __builtin_amdgcn_mfma_f32_16x16x32_bf16(af[m], bw[n], acc1[m][n], 0,0,0);
    }
    // ---- gelu -> hid LDS ----
    #pragma unroll
    for (int m=0;m<2;m++)
      #pragma unroll
      for (int n=0;n<2;n++){
        float bb = b1[hc*96 + pn*32 + n*16 + r16];
        #pragma unroll
        for (int j=0;j<4;j++){
          hid[pm*32 + m*16 + t4*4 + j][pn*32 + n*16 + r16] =
              f2bfbits(fast_gelu(acc1[m][n][j] + bb));
        }
      }
    __syncthreads();
    // ---- fc2 partial over this 96-K chunk ----
    #pragma unroll
    for (int ks=0;ks<3;ks++){
      bf16x8 pa[2];
      #pragma unroll
      for (int m=0;m<2;m++)
        pa[m] = *(const bf16x8*)&hid[pm*32 + m*16 + r16][ks*32 + t4*8];
      #pragma unroll
      for (int n=0;n<4;n++){
        bf16x8 bw2 = *(const bf16x8*)(W2T + (size_t)(pn*64 + n*16 + r16)*768 + hc*96 + ks*32 + t4*8);
        #pragma unroll
        for (int m=0;m<2;m++)
          acc2[m][n] = __builtin_amdgcn_mfma_f32_16x16x32_bf16(pa[m], bw2, acc2[m][n], 0,0,0);
      }
    }
    __syncthreads();   // hid reads done before next chunk overwrites
  }

  // ---- epilogue: +b2 +x2(bf16), token scatter ----
  float b2v[4];
  #pragma unroll
  for (int n=0;n<4;n++) b2v[n] = b2[pn*64 + n*16 + r16];
  #pragma unroll
  for (int m=0;m<2;m++){
    #pragma unroll
    for (int j=0;j<4;j++){
      int lr = pm*32 + m*16 + t4*4 + j;
      size_t pr = (size_t)tokt[lr]*CDIM;
      #pragma unroll
      for (int n=0;n<4;n++){
        size_t p = pr + pn*64 + n*16 + r16;
        out[p] = acc2[m][n][j] + b2v[n] + bfbits2f(x2[p]);
      }
    }
  }
}

// ------- MFMA windowed attention: 4 window-heads per 256-thread block ------
__global__ __launch_bounds__(256) void attn_kernel(
    const uint16_t* __restrict__ qkv, const float* __restrict__ btbl,
    uint16_t* __restrict__ attnout, int win0){
  const int wv   = threadIdx.x >> 6;
  const int lane = threadIdx.x & 63;
  const int whd  = blockIdx.x*4 + wv;
  const int widx = whd/6, hd = whd - widx*6;
  const int r16 = lane & 15, t4 = lane >> 4;
  __shared__ uint16_t Vt[4][32][72];
  __shared__ uint16_t Pl[4][16][72];

  #pragma unroll
  for (int e=lane; e<32*16; e+=64){ Vt[wv][e>>4][48 + (e&15)] = 0; }
  for (int ch = lane; ch < 196; ch += 64){
    int j = ch >> 2, c0 = (ch&3)*8;
    const uint16_t* src = qkv + ((size_t)widx*49 + j)*576 + hd*32 + 384 + c0;
    uint4 v = *(const uint4*)src;
    uint32_t u[4] = {v.x, v.y, v.z, v.w};
    #pragma unroll
    for (int q=0;q<8;q++) Vt[wv][c0+q][j] = (uint16_t)(u[q>>1] >> ((q&1)*16));
  }

  bf16x8 kf[4];
  #pragma unroll
  for (int jt=0;jt<4;jt++)
    kf[jt] = *(const bf16x8*)(qkv + ((size_t)widx*49 + jt*16 + r16)*576 + hd*32 + 192 + t4*8);

  const int gw = win0 + widx;
  const int cls = ((((gw&1023)>>5)==31)<<1) | ((gw&31)==31);
  const float* tb = btbl + ((size_t)(cls*6 + hd) << 12);
  const float scale = 0.17677669529663689f;

  WFENCE;
  bf16x8 bv[2][2];
  #pragma unroll
  for (int ct=0;ct<2;ct++)
    #pragma unroll
    for (int ks=0;ks<2;ks++)
      bv[ct][ks] = *(const bf16x8*)&Vt[wv][ct*16 + r16][ks*32 + t4*8];

  #pragma unroll 2
  for (int it=0; it<4; it++){
    bf16x8 qf = *(const bf16x8*)(qkv + ((size_t)widx*49 + it*16 + r16)*576 + hd*32 + t4*8);
    f32x4 acc[4];
    #pragma unroll
    for (int jt=0;jt<4;jt++){
      acc[jt] = (f32x4){0.f,0.f,0.f,0.f};
      acc[jt] = __builtin_amdgcn_mfma_f32_16x16x32_bf16(kf[jt], qf, acc[jt], 0,0,0);
    }
    int i = it*16 + r16;
    float s[4][4];
    float m = -3.4e38f;
    #pragma unroll
    for (int jt=0;jt<4;jt++){
      float4 bvv = *(const float4*)(tb + i*64 + jt*16 + t4*4);
      float bb[4] = {bvv.x, bvv.y, bvv.z, bvv.w};
      #pragma unroll
      for (int r=0;r<4;r++){
        s[jt][r] = acc[jt][r]*scale + bb[r];
        m = fmaxf(m, s[jt][r]);
      }
    }
    m = fmaxf(m, __shfl_xor(m, 16, 64));
    m = fmaxf(m, __shfl_xor(m, 32, 64));
    float sum = 0.f;
    #pragma unroll
    for (int jt=0;jt<4;jt++)
      #pragma unroll
      for (int r=0;r<4;r++){
        s[jt][r] = __expf(s[jt][r] - m);
        sum += s[jt][r];
      }
    sum += __shfl_xor(sum, 16, 64);
    sum += __shfl_xor(sum, 32, 64);
    float inv = 1.f / sum;
    #pragma unroll
    for (int jt=0;jt<4;jt++){
      uint32_t lo = (uint32_t)f2bfbits(s[jt][0]*inv) | ((uint32_t)f2bfbits(s[jt][1]*inv) << 16);
      uint32_t hi = (uint32_t)f2bfbits(s[jt][2]*inv) | ((uint32_t)f2bfbits(s[jt][3]*inv) << 16);
      *(uint2*)&Pl[wv][r16][jt*16 + t4*4] = make_uint2(lo, hi);
    }
    asm volatile("s_waitcnt lgkmcnt(0)" ::: "memory");

    f32x4 o[2];
    o[0] = (f32x4){0.f,0.f,0.f,0.f};
    o[1] = (f32x4){0.f,0.f,0.f,0.f};
    #pragma unroll
    for (int ks=0;ks<2;ks++){
      bf16x8 pa = *(const bf16x8*)&Pl[wv][r16][ks*32 + t4*8];
      #pragma unroll
      for (int ct=0;ct<2;ct++)
        o[ct] = __builtin_amdgcn_mfma_f32_16x16x32_bf16(pa, bv[ct][ks], o[ct], 0,0,0);
    }
    #pragma unroll
    for (int r=0;r<4;r++){
      int i2 = it*16 + t4*4 + r;
      if (i2 < 49){
        size_t base = ((size_t)widx*49 + i2)*CDIM + hd*32;
        attnout[base + r16]      = f2bfbits(o[0][r]);
        attnout[base + 16 + r16] = f2bfbits(o[1][r]);
      }
    }
  }
}

// ---------------------------------------------------------------------------
extern "C" void kernel_launch(void* const* d_in, const int* in_sizes, int n_in,
                              void* d_out, int out_size, void* d_ws, size_t ws_size,
                              hipStream_t stream) {
  const float* x       = (const float*)d_in[0];
  const float* n1g     = (const float*)d_in[1];
  const float* n1b     = (const float*)d_in[2];
  const float* qkv_w   = (const float*)d_in[3];
  const float* qkv_b   = (const float*)d_in[4];
  const float* rpb     = (const float*)d_in[5];
  const float* proj_w  = (const float*)d_in[6];
  const float* proj_b  = (const float*)d_in[7];
  const float* n2g     = (const float*)d_in[8];
  const float* n2b     = (const float*)d_in[9];
  const float* fc1_w   = (const float*)d_in[10];
  const float* fc1_b   = (const float*)d_in[11];
  const float* fc2_w   = (const float*)d_in[12];
  const float* fc2_b   = (const float*)d_in[13];
  float* out = (float*)d_out;

  const int T = 200704;
  const size_t TBL = 221184 + 73728 + 294912 + 294912 + 393216;
  const size_t ABYTES = (size_t)T*CDIM*2;       // 77.1 MB
  size_t bq_bytes = (size_t)(T/2)*576*2;        // 115.6 MB (half qkv)
  size_t need_full = ABYTES + bq_bytes + ABYTES + TBL;   // ~271 MB
  bool full = ws_size >= need_full;

  char* ws = (char*)d_ws;
  if (full){
    uint16_t* Abuf = (uint16_t*)ws;                      // window-order stage
    uint16_t* Bq   = (uint16_t*)(ws + ABYTES);           // half qkv
    uint16_t* X2   = (uint16_t*)(ws + ABYTES + bq_bytes);// x2 bf16 (token order)
    char* wbase    = ws + ABYTES + bq_bytes + ABYTES;
    uint16_t* qkvW = (uint16_t*)wbase;
    uint16_t* prjW = (uint16_t*)(wbase + 221184);
    uint16_t* fc1W = (uint16_t*)(wbase + 221184 + 73728);
    uint16_t* fc2W = (uint16_t*)(wbase + 221184 + 73728 + 294912);
    float*    btbl = (float*)(wbase + 221184 + 73728 + 294912 + 294912);

    prep_kernel<<<2112, 256, 0, stream>>>(qkv_w, proj_w, fc1_w, fc2_w, rpb,
                                          qkvW, prjW, fc1W, fc2W, btbl);
    const int H = T/2;
    ln1_kernel<<<T/4, 256, 0, stream>>>(x, n1g, n1b, Abuf, 0);
    for (int h=0; h<2; h++){
      uint16_t* Ah = Abuf + (size_t)h*H*CDIM;
      qkv_gemm<<<dim3(9, H/128), 256, 0, stream>>>(Ah, qkvW, qkv_b, Bq);
      attn_kernel<<<(H/49)*6/4, 256, 0, stream>>>(Bq, btbl, Ah, h*(H/49));
    }
    proj_ln2<<<T/64, 384, 0, stream>>>(Abuf, prjW, proj_b, x, n2g, n2b,
                                       X2, Abuf, 0);
    mlp_kernel<<<T/64, 384, 0, stream>>>(Abuf, fc1W, fc2W, fc1_b, fc2_b,
                                         X2, out, 0);
  } else {
    // fallback: per-batch-image chunks (~155 MB)
    const int TC = MB, NW = TC/49;
    uint16_t* Abuf = (uint16_t*)ws;
    uint16_t* Bq   = (uint16_t*)(ws + (size_t)TC*CDIM*2);
    uint16_t* X2   = (uint16_t*)(ws + (size_t)TC*CDIM*2 + (size_t)TC*576*2);
    char* wbase    = ws + (size_t)TC*CDIM*2 + (size_t)TC*576*2 + ABYTES;
    uint16_t* qkvW = (uint16_t*)wbase;
    uint16_t* prjW = (uint16_t*)(wbase + 221184);
    uint16_t* fc1W = (uint16_t*)(wbase + 221184 + 73728);
    uint16_t* fc2W = (uint16_t*)(wbase + 221184 + 73728 + 294912);
    float*    btbl = (float*)(wbase + 221184 + 73728 + 294912 + 294912);

    prep_kernel<<<2112, 256, 0, stream>>>(qkv_w, proj_w, fc1_w, fc2_w, rpb,
                                          qkvW, prjW, fc1W, fc2W, btbl);
    for (int c = 0; c < 4; c++){
      int row0 = c*TC, win0 = row0/49;
      ln1_kernel<<<TC/4, 256, 0, stream>>>(x, n1g, n1b, Abuf, row0);
      qkv_gemm<<<dim3(9, TC/128), 256, 0, stream>>>(Abuf, qkvW, qkv_b, Bq);
      attn_kernel<<<NW*6/4, 256, 0, stream>>>(Bq, btbl, Abuf, win0);
      proj_ln2<<<TC/64, 384, 0, stream>>>(Abuf, prjW, proj_b, x, n2g, n2b,
                                          X2, Abuf, row0);
      mlp_kernel<<<TC/64, 384, 0, stream>>>(Abuf, fc1W, fc2W, fc1_b, fc2_b,
                                            X2, out, row0);
    }
  }
}

// Round 18
// 765.845 us; speedup vs baseline: 1.1184x; 1.1184x over previous
//
#include <hip/hip_runtime.h>
#include <stdint.h>

// ---- problem constants (B=4, H=W=224, C=192, heads=6, win=7, shift=3) ----
#define MB    50176         // tokens per batch image (224*224)
#define CDIM  192

typedef __attribute__((ext_vector_type(8))) short bf16x8;   // MFMA A/B frag (4 VGPR)
typedef __attribute__((ext_vector_type(4))) float f32x4;    // MFMA C/D frag

#define WFENCE do{ asm volatile("s_waitcnt lgkmcnt(0)" ::: "memory"); \
                   __builtin_amdgcn_sched_barrier(0); }while(0)

__device__ __forceinline__ float wsum(float v){
  #pragma unroll
  for (int m=32;m>=1;m>>=1) v += __shfl_xor(v,m,64);
  return v;
}
__device__ __forceinline__ float bfbits2f(uint32_t h){
  union{uint32_t u; float f;} x; x.u = h<<16; return x.f;
}
__device__ __forceinline__ uint16_t f2bfbits(float f){
  union{float ff; uint32_t u;} x; x.ff = f;
  return (uint16_t)((x.u + 0x7FFFu + ((x.u>>16)&1u)) >> 16);
}
__device__ __forceinline__ void gload16(const void* g, void* l){
  __builtin_amdgcn_global_load_lds(
      (const __attribute__((address_space(1))) uint32_t*)g,
      (__attribute__((address_space(3))) uint32_t*)l, 16, 0, 0);
}
// fast gelu: x * sigmoid(1.59576912x + 0.07135481x^3)  (tanh-form, |err|<=3e-4)
__device__ __forceinline__ float fast_gelu(float v){
  float z = v*(1.5957691f + 0.07135481f*v*v);
  return v * __builtin_amdgcn_rcpf(1.f + __expf(-z));
}
// window-order global row -> global token index (roll-back + window-reverse)
__device__ __forceinline__ size_t row2tok(int r_g){
  int widx = r_g/49, tpos = r_g - widx*49;
  int b = widx>>10, rem = widx&1023;
  int h = (rem>>5)*7 + tpos/7 + 3; if (h>=224) h-=224;
  int w = (rem&31)*7 + (tpos - (tpos/7)*7) + 3; if (w>=224) w-=224;
  return (size_t)b*MB + (size_t)h*224 + w;
}

// ---------------- prep: all weight converts (f32 KxN -> bf16 NxK) + btbl ---
__global__ __launch_bounds__(256) void prep_kernel(
    const float* __restrict__ qkv_w, const float* __restrict__ proj_w,
    const float* __restrict__ fc1_w, const float* __restrict__ fc2_w,
    const float* __restrict__ rpb,
    uint16_t* __restrict__ qkvW, uint16_t* __restrict__ prjW,
    uint16_t* __restrict__ fc1W, uint16_t* __restrict__ fc2W,
    float* __restrict__ btbl){
  int idx = blockIdx.x*256 + threadIdx.x;
  if (idx < 110592){ int k=idx/576, n=idx-k*576; qkvW[n*192+k]=f2bfbits(qkv_w[idx]); return; }
  idx -= 110592;
  if (idx < 36864){ int k=idx/192, n=idx-k*192; prjW[n*192+k]=f2bfbits(proj_w[idx]); return; }
  idx -= 36864;
  if (idx < 147456){ int k=idx/768, n=idx-k*768; fc1W[n*192+k]=f2bfbits(fc1_w[idx]); return; }
  idx -= 147456;
  if (idx < 147456){ int k=idx/192, n=idx-k*192; fc2W[n*768+k]=f2bfbits(fc2_w[idx]); return; }
  idx -= 147456;
  if (idx >= 98304) return;
  int j = idx & 63, i = (idx>>6) & 63;
  int hd = (idx>>12) % 6, cls = (idx>>12)/6;
  float v = -1e9f;
  if (i < 49 && j < 49){
    int dh = i/7 - j/7, dw = i%7 - j%7;
    v = rpb[((dh+6)*13 + (dw+6))*6 + hd];
    int cH = cls>>1, cW = cls&1;
    int li = (cH ? (i/7 < 4 ? 1 : 2) : 0)*3 + (cW ? (i%7 < 4 ? 1 : 2) : 0);
    int lj = (cH ? (j/7 < 4 ? 1 : 2) : 0)*3 + (cW ? (j%7 < 4 ? 1 : 2) : 0);
    if (li != lj) v = -1e9f;
  }
  btbl[idx] = v;
}

// ---------------- LN1 + roll + window-partition gather -> bf16 -------------
__global__ __launch_bounds__(256) void ln1_kernel(
    const float* __restrict__ x, const float* __restrict__ g,
    const float* __restrict__ bt, uint16_t* __restrict__ dst, int row0){
  int wid_l = (int)((blockIdx.x*256u + threadIdx.x) >> 6);
  int lane  = threadIdx.x & 63;
  size_t sidx = row2tok(row0 + wid_l);
  const float* s = x + sidx*CDIM;
  float v0=s[lane], v1=s[lane+64], v2=s[lane+128];
  float mu  = wsum(v0+v1+v2) * (1.f/192.f);
  float var = wsum(v0*v0+v1*v1+v2*v2)*(1.f/192.f) - mu*mu;
  float rs  = rsqrtf(var + 1e-5f);
  uint16_t* d = dst + (size_t)wid_l*CDIM;
  d[lane]     = f2bfbits((v0-mu)*rs*g[lane]     + bt[lane]);
  d[lane+64]  = f2bfbits((v1-mu)*rs*g[lane+64]  + bt[lane+64]);
  d[lane+128] = f2bfbits((v2-mu)*rs*g[lane+128] + bt[lane+128]);
}

// ------- MFMA GEMM, r5 geometry + 2-phase dbuf: 128x64 tile, 4 waves -------
// (exactly the r13 code that passed; no block remap)
enum { EPI_QKV=0, EPI_FC1=2, EPI_FC2=3 };

template<int EPI, int K, int NN>
__global__ __launch_bounds__(256) void mgemm(
    const uint16_t* __restrict__ A, const uint16_t* __restrict__ WT,
    const float* __restrict__ bias, void* __restrict__ outp,
    const uint16_t* __restrict__ resid, int row0){
  __shared__ __attribute__((aligned(16))) char As[2][128*128];
  __shared__ __attribute__((aligned(16))) char Bs[2][64*128];
  __shared__ int tokt[128];
  const int tid  = threadIdx.x;
  const int lane = tid & 63;
  const int wid  = tid >> 6;
  const int brow = blockIdx.y * 128;
  const int bcol = blockIdx.x * 64;

  f32x4 acc[4][2];
  #pragma unroll
  for (int m=0;m<4;m++)
    #pragma unroll
    for (int n=0;n<2;n++) acc[m][n] = (f32x4){0.f,0.f,0.f,0.f};

  const int srow = lane >> 3;
  const int sg   = (lane & 7) ^ srow;   // pre-swizzled source granule
  const int wm = wid >> 1, wn = wid & 1;
  const int lrow16 = lane & 15, lkh = lane >> 4;

  if constexpr (EPI==EPI_FC2){
    if (tid < 128) tokt[tid] = (int)row2tok(row0 + brow + tid);
    asm volatile("s_waitcnt lgkmcnt(0)" ::: "memory");
  }

  #define STAGE(k0, Ad, Bd) do{ \
    _Pragma("unroll") \
    for (int c = 0; c < 4; c++){ \
      int ch = wid*4 + c; \
      gload16(A + (size_t)(brow + ch*8 + srow)*K + (k0) + sg*8, (Ad) + ch*1024); \
    } \
    _Pragma("unroll") \
    for (int c = 0; c < 2; c++){ \
      int ch = wid*2 + c; \
      gload16(WT + (size_t)(bcol + ch*8 + srow)*K + (k0) + sg*8, (Bd) + ch*1024); \
    } \
  }while(0)

  constexpr int NK = K/64;
  STAGE(0, As[0], Bs[0]);               // prologue
  #pragma unroll
  for (int ki = 0; ki < NK; ki++){
    const int cur = ki & 1;
    if (ki+1 < NK){
      STAGE((ki+1)*64, As[cur^1], Bs[cur^1]);          // prefetch next tile
      asm volatile("s_waitcnt vmcnt(6)" ::: "memory"); // current tile landed
    } else {
      asm volatile("s_waitcnt vmcnt(0)" ::: "memory");
    }
    __builtin_amdgcn_s_barrier();
    __builtin_amdgcn_sched_barrier(0);

    bf16x8 af[4][2], bfr[2][2];
    #pragma unroll
    for (int m=0;m<4;m++)
      #pragma unroll
      for (int ks=0;ks<2;ks++){
        int arow = wm*64 + m*16 + lrow16;
        af[m][ks] = *(const bf16x8*)(As[cur] + arow*128 + (((ks*4+lkh) ^ (arow&7))<<4));
      }
    #pragma unroll
    for (int n=0;n<2;n++)
      #pragma unroll
      for (int ks=0;ks<2;ks++){
        int brn = wn*32 + n*16 + lrow16;
        bfr[n][ks] = *(const bf16x8*)(Bs[cur] + brn*128 + (((ks*4+lkh) ^ (brn&7))<<4));
      }
    #pragma unroll
    for (int m=0;m<4;m++)
      #pragma unroll
      for (int n=0;n<2;n++)
        #pragma unroll
        for (int ks=0;ks<2;ks++)
          acc[m][n] = __builtin_amdgcn_mfma_f32_16x16x32_bf16(
              af[m][ks], bfr[n][ks], acc[m][n], 0, 0, 0);
    if (ki+1 < NK) __builtin_amdgcn_s_barrier();
  }
  #undef STAGE

  float bi[2];
  #pragma unroll
  for (int n=0;n<2;n++) bi[n] = bias[bcol + wn*32 + n*16 + lrow16];
  #pragma unroll
  for (int m=0;m<4;m++){
    #pragma unroll
    for (int j=0;j<4;j++){
      int lr = wm*64 + m*16 + lkh*4 + j;
      int r  = brow + lr;
      if constexpr (EPI==EPI_QKV || EPI==EPI_FC1){
        #pragma unroll
        for (int n=0;n<2;n++){
          float v = acc[m][n][j] + bi[n];
          if constexpr (EPI==EPI_FC1)
            v = fast_gelu(v);
          ((uint16_t*)outp)[(size_t)r*NN + bcol + wn*32 + n*16 + lrow16] = f2bfbits(v);
        }
      } else { // EPI_FC2: token scatter (LDS table) + bf16 residual(x2)
        size_t pr = (size_t)tokt[lr]*CDIM;
        #pragma unroll
        for (int n=0;n<2;n++){
          size_t p = pr + bcol + wn*32 + n*16 + lrow16;
          ((float*)outp)[p] = acc[m][n][j] + bi[n] + bfbits2f(resid[p]);
        }
      }
    }
  }
}

// ----- proj GEMM (64x192 tile, 6 waves) + fused LN2, 2-phase dbuf ----------
// Counted vmcnt(5) pipeline (per-wave stage count is 5 or 6; 5 drains all
// current-stage loads for every wave). LDS 64K dbuf -> 2 blocks/CU.
__global__ __launch_bounds__(384) void proj_ln2(
    const uint16_t* __restrict__ A, const uint16_t* __restrict__ WT,
    const float* __restrict__ pbias, const float* __restrict__ x,
    const float* __restrict__ g2, const float* __restrict__ b2,
    uint16_t* __restrict__ x2out, uint16_t* __restrict__ ln2out, int row0){
  __shared__ __attribute__((aligned(16))) char As[2][64*128];   // 8KB each
  __shared__ __attribute__((aligned(16))) char Bs[2][192*128];  // 24KB each
  __shared__ float stats[3][64][2];
  __shared__ int tokt[64];
  const int tid  = threadIdx.x;
  const int lane = tid & 63;
  const int wid  = tid >> 6;          // 0..5
  const int pm = wid / 3, pn = wid - pm*3;
  const int brow = blockIdx.x * 64;
  const int srow = lane >> 3;
  const int sg   = (lane & 7) ^ srow;
  const int r16 = lane & 15, t4 = lane >> 4;

  if (tid < 64) tokt[tid] = (int)row2tok(row0 + brow + tid);
  asm volatile("s_waitcnt lgkmcnt(0)" ::: "memory");  // raw barriers: no release

  f32x4 acc[2][4];
  #pragma unroll
  for (int m=0;m<2;m++)
    #pragma unroll
    for (int n=0;n<4;n++) acc[m][n] = (f32x4){0.f,0.f,0.f,0.f};

  #define PSTAGE(k0, Ad, Bd) do{ \
    for (int ch = wid; ch < 8; ch += 6) \
      gload16(A + (size_t)(brow + ch*8 + srow)*192 + (k0) + sg*8, (Ad) + ch*1024); \
    for (int ch = wid; ch < 24; ch += 6) \
      gload16(WT + (size_t)(ch*8 + srow)*192 + (k0) + sg*8, (Bd) + ch*1024); \
  }while(0)

  PSTAGE(0, As[0], Bs[0]);              // prologue
  #pragma unroll
  for (int ki = 0; ki < 3; ki++){
    const int cur = ki & 1;
    if (ki+1 < 3){
      PSTAGE((ki+1)*64, As[cur^1], Bs[cur^1]);         // prefetch next tile
      asm volatile("s_waitcnt vmcnt(5)" ::: "memory"); // current tile landed
    } else {
      asm volatile("s_waitcnt vmcnt(0)" ::: "memory");
    }
    __builtin_amdgcn_s_barrier();
    __builtin_amdgcn_sched_barrier(0);

    bf16x8 af[2][2], bfr[4][2];
    #pragma unroll
    for (int m=0;m<2;m++)
      #pragma unroll
      for (int ks=0;ks<2;ks++){
        int arow = pm*32 + m*16 + r16;
        af[m][ks] = *(const bf16x8*)(As[cur] + arow*128 + (((ks*4+t4) ^ (arow&7))<<4));
      }
    #pragma unroll
    for (int n=0;n<4;n++)
      #pragma unroll
      for (int ks=0;ks<2;ks++){
        int brn = pn*64 + n*16 + r16;
        bfr[n][ks] = *(const bf16x8*)(Bs[cur] + brn*128 + (((ks*4+t4) ^ (brn&7))<<4));
      }
    #pragma unroll
    for (int m=0;m<2;m++)
      #pragma unroll
      for (int n=0;n<4;n++)
        #pragma unroll
        for (int ks=0;ks<2;ks++)
          acc[m][n] = __builtin_amdgcn_mfma_f32_16x16x32_bf16(
              af[m][ks], bfr[n][ks], acc[m][n], 0, 0, 0);
    if (ki+1 < 3) __builtin_amdgcn_s_barrier();        // guard buf reuse
  }
  #undef PSTAGE

  float bi[4], g2v[4], b2v[4];
  #pragma unroll
  for (int n=0;n<4;n++){
    int c = pn*64 + n*16 + r16;
    bi[n] = pbias[c]; g2v[n] = g2[c]; b2v[n] = b2[c];
  }
  // pass 1: y = acc + bias + x[token]; write x2 (bf16); per-row partial stats
  #pragma unroll
  for (int m=0;m<2;m++){
    #pragma unroll
    for (int j=0;j<4;j++){
      int lr = pm*32 + m*16 + t4*4 + j;            // local row in [0,64)
      size_t pr = (size_t)tokt[lr]*CDIM;
      float s1 = 0.f, s2 = 0.f;
      #pragma unroll
      for (int n=0;n<4;n++){
        int c = pn*64 + n*16 + r16;
        float y = acc[m][n][j] + bi[n] + x[pr + c];
        acc[m][n][j] = y;
        x2out[pr + c] = f2bfbits(y);
        s1 += y; s2 = fmaf(y, y, s2);
      }
      #pragma unroll
      for (int mk=1; mk<16; mk<<=1){
        s1 += __shfl_xor(s1, mk, 64);
        s2 += __shfl_xor(s2, mk, 64);
      }
      if (r16 == 0){ stats[pn][lr][0] = s1; stats[pn][lr][1] = s2; }
    }
  }
  __syncthreads();
  // pass 2: normalize, write ln2out (window order, block-local rows)
  #pragma unroll
  for (int m=0;m<2;m++){
    #pragma unroll
    for (int j=0;j<4;j++){
      int lr = pm*32 + m*16 + t4*4 + j;
      float s1 = stats[0][lr][0] + stats[1][lr][0] + stats[2][lr][0];
      float s2 = stats[0][lr][1] + stats[1][lr][1] + stats[2][lr][1];
      float mu = s1*(1.f/192.f);
      float rs = rsqrtf(s2*(1.f/192.f) - mu*mu + 1e-5f);
      size_t wr = (size_t)(brow + lr)*CDIM;
      #pragma unroll
      for (int n=0;n<4;n++){
        int c = pn*64 + n*16 + r16;
        ln2out[wr + c] = f2bfbits((acc[m][n][j]-mu)*rs*g2v[n] + b2v[n]);
      }
    }
  }
}

// ------- MFMA windowed attention: 4 window-heads per 256-thread block ------
__global__ __launch_bounds__(256) void attn_kernel(
    const uint16_t* __restrict__ qkv, const float* __restrict__ btbl,
    uint16_t* __restrict__ attnout, int win0){
  const int wv   = threadIdx.x >> 6;
  const int lane = threadIdx.x & 63;
  const int whd  = blockIdx.x*4 + wv;
  const int widx = whd/6, hd = whd - widx*6;
  const int r16 = lane & 15, t4 = lane >> 4;
  __shared__ uint16_t Vt[4][32][72];
  __shared__ uint16_t Pl[4][16][72];

  #pragma unroll
  for (int e=lane; e<32*16; e+=64){ Vt[wv][e>>4][48 + (e&15)] = 0; }
  for (int ch = lane; ch < 196; ch += 64){
    int j = ch >> 2, c0 = (ch&3)*8;
    const uint16_t* src = qkv + ((size_t)widx*49 + j)*576 + hd*32 + 384 + c0;
    uint4 v = *(const uint4*)src;
    uint32_t u[4] = {v.x, v.y, v.z, v.w};
    #pragma unroll
    for (int q=0;q<8;q++) Vt[wv][c0+q][j] = (uint16_t)(u[q>>1] >> ((q&1)*16));
  }

  bf16x8 kf[4];
  #pragma unroll
  for (int jt=0;jt<4;jt++)
    kf[jt] = *(const bf16x8*)(qkv + ((size_t)widx*49 + jt*16 + r16)*576 + hd*32 + 192 + t4*8);

  const int gw = win0 + widx;
  const int cls = ((((gw&1023)>>5)==31)<<1) | ((gw&31)==31);
  const float* tb = btbl + ((size_t)(cls*6 + hd) << 12);
  const float scale = 0.17677669529663689f;

  WFENCE;
  bf16x8 bv[2][2];
  #pragma unroll
  for (int ct=0;ct<2;ct++)
    #pragma unroll
    for (int ks=0;ks<2;ks++)
      bv[ct][ks] = *(const bf16x8*)&Vt[wv][ct*16 + r16][ks*32 + t4*8];

  #pragma unroll 2
  for (int it=0; it<4; it++){
    bf16x8 qf = *(const bf16x8*)(qkv + ((size_t)widx*49 + it*16 + r16)*576 + hd*32 + t4*8);
    f32x4 acc[4];
    #pragma unroll
    for (int jt=0;jt<4;jt++){
      acc[jt] = (f32x4){0.f,0.f,0.f,0.f};
      acc[jt] = __builtin_amdgcn_mfma_f32_16x16x32_bf16(kf[jt], qf, acc[jt], 0,0,0);
    }
    int i = it*16 + r16;
    float s[4][4];
    float m = -3.4e38f;
    #pragma unroll
    for (int jt=0;jt<4;jt++){
      float4 bvv = *(const float4*)(tb + i*64 + jt*16 + t4*4);
      float bb[4] = {bvv.x, bvv.y, bvv.z, bvv.w};
      #pragma unroll
      for (int r=0;r<4;r++){
        s[jt][r] = acc[jt][r]*scale + bb[r];
        m = fmaxf(m, s[jt][r]);
      }
    }
    m = fmaxf(m, __shfl_xor(m, 16, 64));
    m = fmaxf(m, __shfl_xor(m, 32, 64));
    float sum = 0.f;
    #pragma unroll
    for (int jt=0;jt<4;jt++)
      #pragma unroll
      for (int r=0;r<4;r++){
        s[jt][r] = __expf(s[jt][r] - m);
        sum += s[jt][r];
      }
    sum += __shfl_xor(sum, 16, 64);
    sum += __shfl_xor(sum, 32, 64);
    float inv = 1.f / sum;
    #pragma unroll
    for (int jt=0;jt<4;jt++){
      uint32_t lo = (uint32_t)f2bfbits(s[jt][0]*inv) | ((uint32_t)f2bfbits(s[jt][1]*inv) << 16);
      uint32_t hi = (uint32_t)f2bfbits(s[jt][2]*inv) | ((uint32_t)f2bfbits(s[jt][3]*inv) << 16);
      *(uint2*)&Pl[wv][r16][jt*16 + t4*4] = make_uint2(lo, hi);
    }
    asm volatile("s_waitcnt lgkmcnt(0)" ::: "memory");

    f32x4 o[2];
    o[0] = (f32x4){0.f,0.f,0.f,0.f};
    o[1] = (f32x4){0.f,0.f,0.f,0.f};
    #pragma unroll
    for (int ks=0;ks<2;ks++){
      bf16x8 pa = *(const bf16x8*)&Pl[wv][r16][ks*32 + t4*8];
      #pragma unroll
      for (int ct=0;ct<2;ct++)
        o[ct] = __builtin_amdgcn_mfma_f32_16x16x32_bf16(pa, bv[ct][ks], o[ct], 0,0,0);
    }
    #pragma unroll
    for (int r=0;r<4;r++){
      int i2 = it*16 + t4*4 + r;
      if (i2 < 49){
        size_t base = ((size_t)widx*49 + i2)*CDIM + hd*32;
        attnout[base + r16]      = f2bfbits(o[0][r]);
        attnout[base + 16 + r16] = f2bfbits(o[1][r]);
      }
    }
  }
}

// ---------------------------------------------------------------------------
extern "C" void kernel_launch(void* const* d_in, const int* in_sizes, int n_in,
                              void* d_out, int out_size, void* d_ws, size_t ws_size,
                              hipStream_t stream) {
  const float* x       = (const float*)d_in[0];
  const float* n1g     = (const float*)d_in[1];
  const float* n1b     = (const float*)d_in[2];
  const float* qkv_w   = (const float*)d_in[3];
  const float* qkv_b   = (const float*)d_in[4];
  const float* rpb     = (const float*)d_in[5];
  const float* proj_w  = (const float*)d_in[6];
  const float* proj_b  = (const float*)d_in[7];
  const float* n2g     = (const float*)d_in[8];
  const float* n2b     = (const float*)d_in[9];
  const float* fc1_w   = (const float*)d_in[10];
  const float* fc1_b   = (const float*)d_in[11];
  const float* fc2_w   = (const float*)d_in[12];
  const float* fc2_b   = (const float*)d_in[13];
  float* out = (float*)d_out;

  const int T = 200704;
  const size_t TBL = 221184 + 73728 + 294912 + 294912 + 393216;
  const size_t ABYTES  = (size_t)T*CDIM*2;      // 77.1 MB (Abuf / X2 each)
  size_t bq_bytes = (size_t)(T/2)*768*2;        // 154.1 MB
  size_t need_full = ABYTES + bq_bytes + ABYTES + TBL;   // ~309 MB
  bool full = ws_size >= need_full;

  char* ws = (char*)d_ws;
  if (full){
    uint16_t* Abuf = (uint16_t*)ws;                      // window-order stage
    uint16_t* Bq   = (uint16_t*)(ws + ABYTES);           // half qkv / half hid
    uint16_t* X2   = (uint16_t*)(ws + ABYTES + bq_bytes);// x2 bf16 (token order)
    char* wbase    = ws + ABYTES + bq_bytes + ABYTES;
    uint16_t* qkvW = (uint16_t*)wbase;
    uint16_t* prjW = (uint16_t*)(wbase + 221184);
    uint16_t* fc1W = (uint16_t*)(wbase + 221184 + 73728);
    uint16_t* fc2W = (uint16_t*)(wbase + 221184 + 73728 + 294912);
    float*    btbl = (float*)(wbase + 221184 + 73728 + 294912 + 294912);

    prep_kernel<<<2112, 256, 0, stream>>>(qkv_w, proj_w, fc1_w, fc2_w, rpb,
                                          qkvW, prjW, fc1W, fc2W, btbl);
    const int H = T/2;                 // rows per half
    ln1_kernel<<<T/4, 256, 0, stream>>>(x, n1g, n1b, Abuf, 0);
    for (int h=0; h<2; h++){           // qkv+attn halves
      uint16_t* Ah = Abuf + (size_t)h*H*CDIM;
      mgemm<EPI_QKV, 192, 576>
          <<<dim3(9, H/128), 256, 0, stream>>>(Ah, qkvW, qkv_b, (void*)Bq, nullptr, 0);
      attn_kernel<<<(H/49)*6/4, 256, 0, stream>>>(Bq, btbl, Ah, h*(H/49));
    }
    proj_ln2<<<T/64, 384, 0, stream>>>(Abuf, prjW, proj_b, x, n2g, n2b,
                                       X2, Abuf, 0);
    for (int h=0; h<2; h++){           // fc1+fc2 halves
      uint16_t* Ah = Abuf + (size_t)h*H*CDIM;
      mgemm<EPI_FC1, 192, 768>
          <<<dim3(12, H/128), 256, 0, stream>>>(Ah, fc1W, fc1_b, (void*)Bq, nullptr, 0);
      mgemm<EPI_FC2, 768, 192>
          <<<dim3(3, H/128), 256, 0, stream>>>(Bq, fc2W, fc2_b, (void*)out, X2, h*H);
    }
  } else {
    // fallback: per-batch-image chunks (needs ~175MB)
    const int TC = MB, NW = TC/49;
    uint16_t* Abuf = (uint16_t*)ws;
    uint16_t* Bq   = (uint16_t*)(ws + (size_t)TC*CDIM*2);
    uint16_t* X2   = (uint16_t*)(ws + (size_t)TC*CDIM*2 + (size_t)TC*768*2);
    char* wbase    = ws + (size_t)TC*CDIM*2 + (size_t)TC*768*2 + ABYTES;
    uint16_t* qkvW = (uint16_t*)wbase;
    uint16_t* prjW = (uint16_t*)(wbase + 221184);
    uint16_t* fc1W = (uint16_t*)(wbase + 221184 + 73728);
    uint16_t* fc2W = (uint16_t*)(wbase + 221184 + 73728 + 294912);
    float*    btbl = (float*)(wbase + 221184 + 73728 + 294912 + 294912);

    prep_kernel<<<2112, 256, 0, stream>>>(qkv_w, proj_w, fc1_w, fc2_w, rpb,
                                          qkvW, prjW, fc1W, fc2W, btbl);
    for (int c = 0; c < 4; c++){
      int row0 = c*TC, win0 = row0/49;
      ln1_kernel<<<TC/4, 256, 0, stream>>>(x, n1g, n1b, Abuf, row0);
      mgemm<EPI_QKV, 192, 576>
          <<<dim3(9, TC/128), 256, 0, stream>>>(Abuf, qkvW, qkv_b, (void*)Bq, nullptr, 0);
      attn_kernel<<<NW*6/4, 256, 0, stream>>>(Bq, btbl, Abuf, win0);
      proj_ln2<<<TC/64, 384, 0, stream>>>(Abuf, prjW, proj_b, x, n2g, n2b,
                                          X2, Abuf, row0);
      mgemm<EPI_FC1, 192, 768>
          <<<dim3(12, TC/128), 256, 0, stream>>>(Abuf, fc1W, fc1_b, (void*)Bq, nullptr, 0);
      mgemm<EPI_FC2, 768, 192>
          <<<dim3(3, TC/128), 256, 0, stream>>>(Bq, fc2W, fc2_b, (void*)out, X2, row0);
    }
  }
}

// Round 19
// 736.663 us; speedup vs baseline: 1.1627x; 1.0396x over previous
//
#include <hip/hip_runtime.h>
#include <stdint.h>

// ---- problem constants (B=4, H=W=224, C=192, heads=6, win=7, shift=3) ----
#define MB    50176         // tokens per batch image (224*224)
#define CDIM  192

typedef __attribute__((ext_vector_type(8))) short bf16x8;   // MFMA A/B frag (4 VGPR)
typedef __attribute__((ext_vector_type(4))) float f32x4;    // MFMA C/D frag

#define WFENCE do{ asm volatile("s_waitcnt lgkmcnt(0)" ::: "memory"); \
                   __builtin_amdgcn_sched_barrier(0); }while(0)

__device__ __forceinline__ float wsum(float v){
  #pragma unroll
  for (int m=32;m>=1;m>>=1) v += __shfl_xor(v,m,64);
  return v;
}
__device__ __forceinline__ float bfbits2f(uint32_t h){
  union{uint32_t u; float f;} x; x.u = h<<16; return x.f;
}
__device__ __forceinline__ uint16_t f2bfbits(float f){
  union{float ff; uint32_t u;} x; x.ff = f;
  return (uint16_t)((x.u + 0x7FFFu + ((x.u>>16)&1u)) >> 16);
}
__device__ __forceinline__ void gload16(const void* g, void* l){
  __builtin_amdgcn_global_load_lds(
      (const __attribute__((address_space(1))) uint32_t*)g,
      (__attribute__((address_space(3))) uint32_t*)l, 16, 0, 0);
}
// fast gelu: x * sigmoid(1.59576912x + 0.07135481x^3)  (tanh-form, |err|<=3e-4)
__device__ __forceinline__ float fast_gelu(float v){
  float z = v*(1.5957691f + 0.07135481f*v*v);
  return v * __builtin_amdgcn_rcpf(1.f + __expf(-z));
}
// window-order global row -> global token index (roll-back + window-reverse)
__device__ __forceinline__ size_t row2tok(int r_g){
  int widx = r_g/49, tpos = r_g - widx*49;
  int b = widx>>10, rem = widx&1023;
  int h = (rem>>5)*7 + tpos/7 + 3; if (h>=224) h-=224;
  int w = (rem&31)*7 + (tpos - (tpos/7)*7) + 3; if (w>=224) w-=224;
  return (size_t)b*MB + (size_t)h*224 + w;
}

// ---------------- prep: all weight converts (f32 KxN -> bf16 NxK) + btbl ---
__global__ __launch_bounds__(256) void prep_kernel(
    const float* __restrict__ qkv_w, const float* __restrict__ proj_w,
    const float* __restrict__ fc1_w, const float* __restrict__ fc2_w,
    const float* __restrict__ rpb,
    uint16_t* __restrict__ qkvW, uint16_t* __restrict__ prjW,
    uint16_t* __restrict__ fc1W, uint16_t* __restrict__ fc2W,
    float* __restrict__ btbl){
  int idx = blockIdx.x*256 + threadIdx.x;
  if (idx < 110592){ int k=idx/576, n=idx-k*576; qkvW[n*192+k]=f2bfbits(qkv_w[idx]); return; }
  idx -= 110592;
  if (idx < 36864){ int k=idx/192, n=idx-k*192; prjW[n*192+k]=f2bfbits(proj_w[idx]); return; }
  idx -= 36864;
  if (idx < 147456){ int k=idx/768, n=idx-k*768; fc1W[n*192+k]=f2bfbits(fc1_w[idx]); return; }
  idx -= 147456;
  if (idx < 147456){ int k=idx/192, n=idx-k*192; fc2W[n*768+k]=f2bfbits(fc2_w[idx]); return; }
  idx -= 147456;
  if (idx >= 98304) return;
  int j = idx & 63, i = (idx>>6) & 63;
  int hd = (idx>>12) % 6, cls = (idx>>12)/6;
  float v = -1e9f;
  if (i < 49 && j < 49){
    int dh = i/7 - j/7, dw = i%7 - j%7;
    v = rpb[((dh+6)*13 + (dw+6))*6 + hd];
    int cH = cls>>1, cW = cls&1;
    int li = (cH ? (i/7 < 4 ? 1 : 2) : 0)*3 + (cW ? (i%7 < 4 ? 1 : 2) : 0);
    int lj = (cH ? (j/7 < 4 ? 1 : 2) : 0)*3 + (cW ? (j%7 < 4 ? 1 : 2) : 0);
    if (li != lj) v = -1e9f;
  }
  btbl[idx] = v;
}

// ---------------- LN1 + roll + window-partition gather -> bf16 -------------
__global__ __launch_bounds__(256) void ln1_kernel(
    const float* __restrict__ x, const float* __restrict__ g,
    const float* __restrict__ bt, uint16_t* __restrict__ dst, int row0){
  int wid_l = (int)((blockIdx.x*256u + threadIdx.x) >> 6);
  int lane  = threadIdx.x & 63;
  size_t sidx = row2tok(row0 + wid_l);
  const float* s = x + sidx*CDIM;
  float v0=s[lane], v1=s[lane+64], v2=s[lane+128];
  float mu  = wsum(v0+v1+v2) * (1.f/192.f);
  float var = wsum(v0*v0+v1*v1+v2*v2)*(1.f/192.f) - mu*mu;
  float rs  = rsqrtf(var + 1e-5f);
  uint16_t* d = dst + (size_t)wid_l*CDIM;
  d[lane]     = f2bfbits((v0-mu)*rs*g[lane]     + bt[lane]);
  d[lane+64]  = f2bfbits((v1-mu)*rs*g[lane+64]  + bt[lane+64]);
  d[lane+128] = f2bfbits((v2-mu)*rs*g[lane+128] + bt[lane+128]);
}

// ------- MFMA GEMM, r5 geometry + 2-phase dbuf: 128x64 tile, 4 waves -------
enum { EPI_QKV=0, EPI_FC1=2, EPI_FC2=3 };

template<int EPI, int K, int NN>
__global__ __launch_bounds__(256) void mgemm(
    const uint16_t* __restrict__ A, const uint16_t* __restrict__ WT,
    const float* __restrict__ bias, void* __restrict__ outp,
    const uint16_t* __restrict__ resid, int row0){
  __shared__ __attribute__((aligned(16))) char As[2][128*128];
  __shared__ __attribute__((aligned(16))) char Bs[2][64*128];
  __shared__ int tokt[128];
  const int tid  = threadIdx.x;
  const int lane = tid & 63;
  const int wid  = tid >> 6;
  const int brow = blockIdx.y * 128;
  const int bcol = blockIdx.x * 64;

  f32x4 acc[4][2];
  #pragma unroll
  for (int m=0;m<4;m++)
    #pragma unroll
    for (int n=0;n<2;n++) acc[m][n] = (f32x4){0.f,0.f,0.f,0.f};

  const int srow = lane >> 3;
  const int sg   = (lane & 7) ^ srow;   // pre-swizzled source granule
  const int wm = wid >> 1, wn = wid & 1;
  const int lrow16 = lane & 15, lkh = lane >> 4;

  if constexpr (EPI==EPI_FC2){
    if (tid < 128) tokt[tid] = (int)row2tok(row0 + brow + tid);
    asm volatile("s_waitcnt lgkmcnt(0)" ::: "memory");
  }

  #define STAGE(k0, Ad, Bd) do{ \
    _Pragma("unroll") \
    for (int c = 0; c < 4; c++){ \
      int ch = wid*4 + c; \
      gload16(A + (size_t)(brow + ch*8 + srow)*K + (k0) + sg*8, (Ad) + ch*1024); \
    } \
    _Pragma("unroll") \
    for (int c = 0; c < 2; c++){ \
      int ch = wid*2 + c; \
      gload16(WT + (size_t)(bcol + ch*8 + srow)*K + (k0) + sg*8, (Bd) + ch*1024); \
    } \
  }while(0)

  constexpr int NK = K/64;
  STAGE(0, As[0], Bs[0]);               // prologue
  #pragma unroll
  for (int ki = 0; ki < NK; ki++){
    const int cur = ki & 1;
    if (ki+1 < NK){
      STAGE((ki+1)*64, As[cur^1], Bs[cur^1]);          // prefetch next tile
      asm volatile("s_waitcnt vmcnt(6)" ::: "memory"); // current tile landed
    } else {
      asm volatile("s_waitcnt vmcnt(0)" ::: "memory");
    }
    __builtin_amdgcn_s_barrier();
    __builtin_amdgcn_sched_barrier(0);

    bf16x8 af[4][2], bfr[2][2];
    #pragma unroll
    for (int m=0;m<4;m++)
      #pragma unroll
      for (int ks=0;ks<2;ks++){
        int arow = wm*64 + m*16 + lrow16;
        af[m][ks] = *(const bf16x8*)(As[cur] + arow*128 + (((ks*4+lkh) ^ (arow&7))<<4));
      }
    #pragma unroll
    for (int n=0;n<2;n++)
      #pragma unroll
      for (int ks=0;ks<2;ks++){
        int brn = wn*32 + n*16 + lrow16;
        bfr[n][ks] = *(const bf16x8*)(Bs[cur] + brn*128 + (((ks*4+lkh) ^ (brn&7))<<4));
      }
    #pragma unroll
    for (int m=0;m<4;m++)
      #pragma unroll
      for (int n=0;n<2;n++)
        #pragma unroll
        for (int ks=0;ks<2;ks++)
          acc[m][n] = __builtin_amdgcn_mfma_f32_16x16x32_bf16(
              af[m][ks], bfr[n][ks], acc[m][n], 0, 0, 0);
    if (ki+1 < NK) __builtin_amdgcn_s_barrier();
  }
  #undef STAGE

  float bi[2];
  #pragma unroll
  for (int n=0;n<2;n++) bi[n] = bias[bcol + wn*32 + n*16 + lrow16];
  #pragma unroll
  for (int m=0;m<4;m++){
    #pragma unroll
    for (int j=0;j<4;j++){
      int lr = wm*64 + m*16 + lkh*4 + j;
      int r  = brow + lr;
      if constexpr (EPI==EPI_QKV || EPI==EPI_FC1){
        #pragma unroll
        for (int n=0;n<2;n++){
          float v = acc[m][n][j] + bi[n];
          if constexpr (EPI==EPI_FC1)
            v = fast_gelu(v);
          ((uint16_t*)outp)[(size_t)r*NN + bcol + wn*32 + n*16 + lrow16] = f2bfbits(v);
        }
      } else { // EPI_FC2: token scatter (LDS table) + bf16 residual(x2)
        size_t pr = (size_t)tokt[lr]*CDIM;
        #pragma unroll
        for (int n=0;n<2;n++){
          size_t p = pr + bcol + wn*32 + n*16 + lrow16;
          ((float*)outp)[p] = acc[m][n][j] + bi[n] + bfbits2f(resid[p]);
        }
      }
    }
  }
}

// ----- proj GEMM (64x192 tile, 6 waves, wave 32x64) + fused LN2 ------------
// single-buffered (34.8KB LDS -> 4 blocks/CU): measured optimum (r12/r13).
__global__ __launch_bounds__(384) void proj_ln2(
    const uint16_t* __restrict__ A, const uint16_t* __restrict__ WT,
    const float* __restrict__ pbias, const float* __restrict__ x,
    const float* __restrict__ g2, const float* __restrict__ b2,
    uint16_t* __restrict__ x2out, uint16_t* __restrict__ ln2out, int row0){
  __shared__ __attribute__((aligned(16))) char As[64*128];    // [64][64k]
  __shared__ __attribute__((aligned(16))) char Bs[192*128];   // [192][64k]
  __shared__ float stats[3][64][2];
  __shared__ int tokt[64];
  const int tid  = threadIdx.x;
  const int lane = tid & 63;
  const int wid  = tid >> 6;          // 0..5
  const int pm = wid / 3, pn = wid - pm*3;
  const int brow = blockIdx.x * 64;
  const int srow = lane >> 3;
  const int sg   = (lane & 7) ^ srow;
  const int r16 = lane & 15, t4 = lane >> 4;

  if (tid < 64) tokt[tid] = (int)row2tok(row0 + brow + tid);

  f32x4 acc[2][4];
  #pragma unroll
  for (int m=0;m<2;m++)
    #pragma unroll
    for (int n=0;n<4;n++) acc[m][n] = (f32x4){0.f,0.f,0.f,0.f};

  for (int k0 = 0; k0 < 192; k0 += 64){
    for (int ch = wid; ch < 8; ch += 6)
      gload16(A + (size_t)(brow + ch*8 + srow)*192 + k0 + sg*8, As + ch*1024);
    for (int ch = wid; ch < 24; ch += 6)
      gload16(WT + (size_t)(ch*8 + srow)*192 + k0 + sg*8, Bs + ch*1024);
    __syncthreads();

    bf16x8 af[2][2], bfr[4][2];
    #pragma unroll
    for (int m=0;m<2;m++)
      #pragma unroll
      for (int ks=0;ks<2;ks++){
        int arow = pm*32 + m*16 + r16;
        af[m][ks] = *(const bf16x8*)(As + arow*128 + (((ks*4+t4) ^ (arow&7))<<4));
      }
    #pragma unroll
    for (int n=0;n<4;n++)
      #pragma unroll
      for (int ks=0;ks<2;ks++){
        int brn = pn*64 + n*16 + r16;
        bfr[n][ks] = *(const bf16x8*)(Bs + brn*128 + (((ks*4+t4) ^ (brn&7))<<4));
      }
    #pragma unroll
    for (int m=0;m<2;m++)
      #pragma unroll
      for (int n=0;n<4;n++)
        #pragma unroll
        for (int ks=0;ks<2;ks++)
          acc[m][n] = __builtin_amdgcn_mfma_f32_16x16x32_bf16(
              af[m][ks], bfr[n][ks], acc[m][n], 0, 0, 0);
    __syncthreads();
  }

  float bi[4], g2v[4], b2v[4];
  #pragma unroll
  for (int n=0;n<4;n++){
    int c = pn*64 + n*16 + r16;
    bi[n] = pbias[c]; g2v[n] = g2[c]; b2v[n] = b2[c];
  }
  // pass 1: y = acc + bias + x[token]; write x2 (bf16); per-row partial stats
  #pragma unroll
  for (int m=0;m<2;m++){
    #pragma unroll
    for (int j=0;j<4;j++){
      int lr = pm*32 + m*16 + t4*4 + j;            // local row in [0,64)
      size_t pr = (size_t)tokt[lr]*CDIM;
      float s1 = 0.f, s2 = 0.f;
      #pragma unroll
      for (int n=0;n<4;n++){
        int c = pn*64 + n*16 + r16;
        float y = acc[m][n][j] + bi[n] + x[pr + c];
        acc[m][n][j] = y;
        x2out[pr + c] = f2bfbits(y);
        s1 += y; s2 = fmaf(y, y, s2);
      }
      #pragma unroll
      for (int mk=1; mk<16; mk<<=1){
        s1 += __shfl_xor(s1, mk, 64);
        s2 += __shfl_xor(s2, mk, 64);
      }
      if (r16 == 0){ stats[pn][lr][0] = s1; stats[pn][lr][1] = s2; }
    }
  }
  __syncthreads();
  // pass 2: normalize, write ln2out (window order, block-local rows)
  #pragma unroll
  for (int m=0;m<2;m++){
    #pragma unroll
    for (int j=0;j<4;j++){
      int lr = pm*32 + m*16 + t4*4 + j;
      float s1 = stats[0][lr][0] + stats[1][lr][0] + stats[2][lr][0];
      float s2 = stats[0][lr][1] + stats[1][lr][1] + stats[2][lr][1];
      float mu = s1*(1.f/192.f);
      float rs = rsqrtf(s2*(1.f/192.f) - mu*mu + 1e-5f);
      size_t wr = (size_t)(brow + lr)*CDIM;
      #pragma unroll
      for (int n=0;n<4;n++){
        int c = pn*64 + n*16 + r16;
        ln2out[wr + c] = f2bfbits((acc[m][n][j]-mu)*rs*g2v[n] + b2v[n]);
      }
    }
  }
}

// ------- MFMA windowed attention: 4 window-heads per 256-thread block ------
__global__ __launch_bounds__(256) void attn_kernel(
    const uint16_t* __restrict__ qkv, const float* __restrict__ btbl,
    uint16_t* __restrict__ attnout, int win0){
  const int wv   = threadIdx.x >> 6;
  const int lane = threadIdx.x & 63;
  const int whd  = blockIdx.x*4 + wv;
  const int widx = whd/6, hd = whd - widx*6;
  const int r16 = lane & 15, t4 = lane >> 4;
  __shared__ uint16_t Vt[4][32][72];
  __shared__ uint16_t Pl[4][16][72];

  #pragma unroll
  for (int e=lane; e<32*16; e+=64){ Vt[wv][e>>4][48 + (e&15)] = 0; }
  for (int ch = lane; ch < 196; ch += 64){
    int j = ch >> 2, c0 = (ch&3)*8;
    const uint16_t* src = qkv + ((size_t)widx*49 + j)*576 + hd*32 + 384 + c0;
    uint4 v = *(const uint4*)src;
    uint32_t u[4] = {v.x, v.y, v.z, v.w};
    #pragma unroll
    for (int q=0;q<8;q++) Vt[wv][c0+q][j] = (uint16_t)(u[q>>1] >> ((q&1)*16));
  }

  bf16x8 kf[4];
  #pragma unroll
  for (int jt=0;jt<4;jt++)
    kf[jt] = *(const bf16x8*)(qkv + ((size_t)widx*49 + jt*16 + r16)*576 + hd*32 + 192 + t4*8);

  const int gw = win0 + widx;
  const int cls = ((((gw&1023)>>5)==31)<<1) | ((gw&31)==31);
  const float* tb = btbl + ((size_t)(cls*6 + hd) << 12);
  const float scale = 0.17677669529663689f;

  WFENCE;
  bf16x8 bv[2][2];
  #pragma unroll
  for (int ct=0;ct<2;ct++)
    #pragma unroll
    for (int ks=0;ks<2;ks++)
      bv[ct][ks] = *(const bf16x8*)&Vt[wv][ct*16 + r16][ks*32 + t4*8];

  #pragma unroll 2
  for (int it=0; it<4; it++){
    bf16x8 qf = *(const bf16x8*)(qkv + ((size_t)widx*49 + it*16 + r16)*576 + hd*32 + t4*8);
    f32x4 acc[4];
    #pragma unroll
    for (int jt=0;jt<4;jt++){
      acc[jt] = (f32x4){0.f,0.f,0.f,0.f};
      acc[jt] = __builtin_amdgcn_mfma_f32_16x16x32_bf16(kf[jt], qf, acc[jt], 0,0,0);
    }
    int i = it*16 + r16;
    float s[4][4];
    float m = -3.4e38f;
    #pragma unroll
    for (int jt=0;jt<4;jt++){
      float4 bvv = *(const float4*)(tb + i*64 + jt*16 + t4*4);
      float bb[4] = {bvv.x, bvv.y, bvv.z, bvv.w};
      #pragma unroll
      for (int r=0;r<4;r++){
        s[jt][r] = acc[jt][r]*scale + bb[r];
        m = fmaxf(m, s[jt][r]);
      }
    }
    m = fmaxf(m, __shfl_xor(m, 16, 64));
    m = fmaxf(m, __shfl_xor(m, 32, 64));
    float sum = 0.f;
    #pragma unroll
    for (int jt=0;jt<4;jt++)
      #pragma unroll
      for (int r=0;r<4;r++){
        s[jt][r] = __expf(s[jt][r] - m);
        sum += s[jt][r];
      }
    sum += __shfl_xor(sum, 16, 64);
    sum += __shfl_xor(sum, 32, 64);
    float inv = 1.f / sum;
    #pragma unroll
    for (int jt=0;jt<4;jt++){
      uint32_t lo = (uint32_t)f2bfbits(s[jt][0]*inv) | ((uint32_t)f2bfbits(s[jt][1]*inv) << 16);
      uint32_t hi = (uint32_t)f2bfbits(s[jt][2]*inv) | ((uint32_t)f2bfbits(s[jt][3]*inv) << 16);
      *(uint2*)&Pl[wv][r16][jt*16 + t4*4] = make_uint2(lo, hi);
    }
    asm volatile("s_waitcnt lgkmcnt(0)" ::: "memory");

    f32x4 o[2];
    o[0] = (f32x4){0.f,0.f,0.f,0.f};
    o[1] = (f32x4){0.f,0.f,0.f,0.f};
    #pragma unroll
    for (int ks=0;ks<2;ks++){
      bf16x8 pa = *(const bf16x8*)&Pl[wv][r16][ks*32 + t4*8];
      #pragma unroll
      for (int ct=0;ct<2;ct++)
        o[ct] = __builtin_amdgcn_mfma_f32_16x16x32_bf16(pa, bv[ct][ks], o[ct], 0,0,0);
    }
    #pragma unroll
    for (int r=0;r<4;r++){
      int i2 = it*16 + t4*4 + r;
      if (i2 < 49){
        size_t base = ((size_t)widx*49 + i2)*CDIM + hd*32;
        attnout[base + r16]      = f2bfbits(o[0][r]);
        attnout[base + 16 + r16] = f2bfbits(o[1][r]);
      }
    }
  }
}

// ---------------------------------------------------------------------------
extern "C" void kernel_launch(void* const* d_in, const int* in_sizes, int n_in,
                              void* d_out, int out_size, void* d_ws, size_t ws_size,
                              hipStream_t stream) {
  const float* x       = (const float*)d_in[0];
  const float* n1g     = (const float*)d_in[1];
  const float* n1b     = (const float*)d_in[2];
  const float* qkv_w   = (const float*)d_in[3];
  const float* qkv_b   = (const float*)d_in[4];
  const float* rpb     = (const float*)d_in[5];
  const float* proj_w  = (const float*)d_in[6];
  const float* proj_b  = (const float*)d_in[7];
  const float* n2g     = (const float*)d_in[8];
  const float* n2b     = (const float*)d_in[9];
  const float* fc1_w   = (const float*)d_in[10];
  const float* fc1_b   = (const float*)d_in[11];
  const float* fc2_w   = (const float*)d_in[12];
  const float* fc2_b   = (const float*)d_in[13];
  float* out = (float*)d_out;

  const int T = 200704;
  const size_t TBL = 221184 + 73728 + 294912 + 294912 + 393216;
  const size_t ABYTES  = (size_t)T*CDIM*2;      // 77.1 MB (Abuf / X2 each)
  size_t bq_bytes = (size_t)(T/2)*768*2;        // 154.1 MB
  size_t need_full = ABYTES + bq_bytes + ABYTES + TBL;   // ~309 MB
  bool full = ws_size >= need_full;

  char* ws = (char*)d_ws;
  if (full){
    uint16_t* Abuf = (uint16_t*)ws;                      // window-order stage
    uint16_t* Bq   = (uint16_t*)(ws + ABYTES);           // half qkv / half hid
    uint16_t* X2   = (uint16_t*)(ws + ABYTES + bq_bytes);// x2 bf16 (token order)
    char* wbase    = ws + ABYTES + bq_bytes + ABYTES;
    uint16_t* qkvW = (uint16_t*)wbase;
    uint16_t* prjW = (uint16_t*)(wbase + 221184);
    uint16_t* fc1W = (uint16_t*)(wbase + 221184 + 73728);
    uint16_t* fc2W = (uint16_t*)(wbase + 221184 + 73728 + 294912);
    float*    btbl = (float*)(wbase + 221184 + 73728 + 294912 + 294912);

    prep_kernel<<<2112, 256, 0, stream>>>(qkv_w, proj_w, fc1_w, fc2_w, rpb,
                                          qkvW, prjW, fc1W, fc2W, btbl);
    const int H = T/2;                 // rows per half
    ln1_kernel<<<T/4, 256, 0, stream>>>(x, n1g, n1b, Abuf, 0);
    for (int h=0; h<2; h++){           // qkv+attn halves
      uint16_t* Ah = Abuf + (size_t)h*H*CDIM;
      mgemm<EPI_QKV, 192, 576>
          <<<dim3(9, H/128), 256, 0, stream>>>(Ah, qkvW, qkv_b, (void*)Bq, nullptr, 0);
      attn_kernel<<<(H/49)*6/4, 256, 0, stream>>>(Bq, btbl, Ah, h*(H/49));
    }
    proj_ln2<<<T/64, 384, 0, stream>>>(Abuf, prjW, proj_b, x, n2g, n2b,
                                       X2, Abuf, 0);
    for (int h=0; h<2; h++){           // fc1+fc2 halves
      uint16_t* Ah = Abuf + (size_t)h*H*CDIM;
      mgemm<EPI_FC1, 192, 768>
          <<<dim3(12, H/128), 256, 0, stream>>>(Ah, fc1W, fc1_b, (void*)Bq, nullptr, 0);
      mgemm<EPI_FC2, 768, 192>
          <<<dim3(3, H/128), 256, 0, stream>>>(Bq, fc2W, fc2_b, (void*)out, X2, h*H);
    }
  } else {
    // fallback: per-batch-image chunks (needs ~175MB)
    const int TC = MB, NW = TC/49;
    uint16_t* Abuf = (uint16_t*)ws;
    uint16_t* Bq   = (uint16_t*)(ws + (size_t)TC*CDIM*2);
    uint16_t* X2   = (uint16_t*)(ws + (size_t)TC*CDIM*2 + (size_t)TC*768*2);
    char* wbase    = ws + (size_t)TC*CDIM*2 + (size_t)TC*768*2 + ABYTES;
    uint16_t* qkvW = (uint16_t*)wbase;
    uint16_t* prjW = (uint16_t*)(wbase + 221184);
    uint16_t* fc1W = (uint16_t*)(wbase + 221184 + 73728);
    uint16_t* fc2W = (uint16_t*)(wbase + 221184 + 73728 + 294912);
    float*    btbl = (float*)(wbase + 221184 + 73728 + 294912 + 294912);

    prep_kernel<<<2112, 256, 0, stream>>>(qkv_w, proj_w, fc1_w, fc2_w, rpb,
                                          qkvW, prjW, fc1W, fc2W, btbl);
    for (int c = 0; c < 4; c++){
      int row0 = c*TC, win0 = row0/49;
      ln1_kernel<<<TC/4, 256, 0, stream>>>(x, n1g, n1b, Abuf, row0);
      mgemm<EPI_QKV, 192, 576>
          <<<dim3(9, TC/128), 256, 0, stream>>>(Abuf, qkvW, qkv_b, (void*)Bq, nullptr, 0);
      attn_kernel<<<NW*6/4, 256, 0, stream>>>(Bq, btbl, Abuf, win0);
      proj_ln2<<<TC/64, 384, 0, stream>>>(Abuf, prjW, proj_b, x, n2g, n2b,
                                          X2, Abuf, row0);
      mgemm<EPI_FC1, 192, 768>
          <<<dim3(12, TC/128), 256, 0, stream>>>(Abuf, fc1W, fc1_b, (void*)Bq, nullptr, 0);
      mgemm<EPI_FC2, 768, 192>
          <<<dim3(3, TC/128), 256, 0, stream>>>(Bq, fc2W, fc2_b, (void*)out, X2, row0);
    }
  }
}

// Round 20
// 718.575 us; speedup vs baseline: 1.1920x; 1.0252x over previous
//
#include <hip/hip_runtime.h>
#include <stdint.h>

// ---- problem constants (B=4, H=W=224, C=192, heads=6, win=7, shift=3) ----
#define MB    50176         // tokens per batch image (224*224)
#define CDIM  192

typedef __attribute__((ext_vector_type(8))) short bf16x8;   // MFMA A/B frag (4 VGPR)
typedef __attribute__((ext_vector_type(4))) float f32x4;    // MFMA C/D frag

#define WFENCE do{ asm volatile("s_waitcnt lgkmcnt(0)" ::: "memory"); \
                   __builtin_amdgcn_sched_barrier(0); }while(0)

__device__ __forceinline__ float wsum(float v){
  #pragma unroll
  for (int m=32;m>=1;m>>=1) v += __shfl_xor(v,m,64);
  return v;
}
__device__ __forceinline__ float bfbits2f(uint32_t h){
  union{uint32_t u; float f;} x; x.u = h<<16; return x.f;
}
__device__ __forceinline__ uint16_t f2bfbits(float f){
  union{float ff; uint32_t u;} x; x.ff = f;
  return (uint16_t)((x.u + 0x7FFFu + ((x.u>>16)&1u)) >> 16);
}
__device__ __forceinline__ void gload16(const void* g, void* l){
  __builtin_amdgcn_global_load_lds(
      (const __attribute__((address_space(1))) uint32_t*)g,
      (__attribute__((address_space(3))) uint32_t*)l, 16, 0, 0);
}
// fast gelu: x * sigmoid(1.59576912x + 0.07135481x^3)  (tanh-form, |err|<=3e-4)
__device__ __forceinline__ float fast_gelu(float v){
  float z = v*(1.5957691f + 0.07135481f*v*v);
  return v * __builtin_amdgcn_rcpf(1.f + __expf(-z));
}
// window-order global row -> global token index (roll-back + window-reverse)
__device__ __forceinline__ size_t row2tok(int r_g){
  int widx = r_g/49, tpos = r_g - widx*49;
  int b = widx>>10, rem = widx&1023;
  int h = (rem>>5)*7 + tpos/7 + 3; if (h>=224) h-=224;
  int w = (rem&31)*7 + (tpos - (tpos/7)*7) + 3; if (w>=224) w-=224;
  return (size_t)b*MB + (size_t)h*224 + w;
}

// ---------------- prep: all weight converts (f32 KxN -> bf16 NxK) + btbl ---
__global__ __launch_bounds__(256) void prep_kernel(
    const float* __restrict__ qkv_w, const float* __restrict__ proj_w,
    const float* __restrict__ fc1_w, const float* __restrict__ fc2_w,
    const float* __restrict__ rpb,
    uint16_t* __restrict__ qkvW, uint16_t* __restrict__ prjW,
    uint16_t* __restrict__ fc1W, uint16_t* __restrict__ fc2W,
    float* __restrict__ btbl){
  int idx = blockIdx.x*256 + threadIdx.x;
  if (idx < 110592){ int k=idx/576, n=idx-k*576; qkvW[n*192+k]=f2bfbits(qkv_w[idx]); return; }
  idx -= 110592;
  if (idx < 36864){ int k=idx/192, n=idx-k*192; prjW[n*192+k]=f2bfbits(proj_w[idx]); return; }
  idx -= 36864;
  if (idx < 147456){ int k=idx/768, n=idx-k*768; fc1W[n*192+k]=f2bfbits(fc1_w[idx]); return; }
  idx -= 147456;
  if (idx < 147456){ int k=idx/192, n=idx-k*192; fc2W[n*768+k]=f2bfbits(fc2_w[idx]); return; }
  idx -= 147456;
  if (idx >= 98304) return;
  int j = idx & 63, i = (idx>>6) & 63;
  int hd = (idx>>12) % 6, cls = (idx>>12)/6;
  float v = -1e9f;
  if (i < 49 && j < 49){
    int dh = i/7 - j/7, dw = i%7 - j%7;
    v = rpb[((dh+6)*13 + (dw+6))*6 + hd];
    int cH = cls>>1, cW = cls&1;
    int li = (cH ? (i/7 < 4 ? 1 : 2) : 0)*3 + (cW ? (i%7 < 4 ? 1 : 2) : 0);
    int lj = (cH ? (j/7 < 4 ? 1 : 2) : 0)*3 + (cW ? (j%7 < 4 ? 1 : 2) : 0);
    if (li != lj) v = -1e9f;
  }
  btbl[idx] = v;
}

// ---------------- LN1 + roll + window-partition gather -> bf16 -------------
__global__ __launch_bounds__(256) void ln1_kernel(
    const float* __restrict__ x, const float* __restrict__ g,
    const float* __restrict__ bt, uint16_t* __restrict__ dst, int row0){
  int wid_l = (int)((blockIdx.x*256u + threadIdx.x) >> 6);
  int lane  = threadIdx.x & 63;
  size_t sidx = row2tok(row0 + wid_l);
  const float* s = x + sidx*CDIM;
  float v0=s[lane], v1=s[lane+64], v2=s[lane+128];
  float mu  = wsum(v0+v1+v2) * (1.f/192.f);
  float var = wsum(v0*v0+v1*v1+v2*v2)*(1.f/192.f) - mu*mu;
  float rs  = rsqrtf(var + 1e-5f);
  uint16_t* d = dst + (size_t)wid_l*CDIM;
  d[lane]     = f2bfbits((v0-mu)*rs*g[lane]     + bt[lane]);
  d[lane+64]  = f2bfbits((v1-mu)*rs*g[lane+64]  + bt[lane+64]);
  d[lane+128] = f2bfbits((v2-mu)*rs*g[lane+128] + bt[lane+128]);
}

// ------- MFMA GEMM, r5 geometry + 2-phase dbuf: 128x64 tile, 4 waves -------
enum { EPI_QKV=0, EPI_FC1=2, EPI_FC2=3 };

template<int EPI, int K, int NN>
__global__ __launch_bounds__(256) void mgemm(
    const uint16_t* __restrict__ A, const uint16_t* __restrict__ WT,
    const float* __restrict__ bias, void* __restrict__ outp,
    const uint16_t* __restrict__ resid, int row0){
  __shared__ __attribute__((aligned(16))) char As[2][128*128];
  __shared__ __attribute__((aligned(16))) char Bs[2][64*128];
  __shared__ int tokt[128];
  const int tid  = threadIdx.x;
  const int lane = tid & 63;
  const int wid  = tid >> 6;
  const int brow = blockIdx.y * 128;
  const int bcol = blockIdx.x * 64;

  f32x4 acc[4][2];
  #pragma unroll
  for (int m=0;m<4;m++)
    #pragma unroll
    for (int n=0;n<2;n++) acc[m][n] = (f32x4){0.f,0.f,0.f,0.f};

  const int srow = lane >> 3;
  const int sg   = (lane & 7) ^ srow;   // pre-swizzled source granule
  const int wm = wid >> 1, wn = wid & 1;
  const int lrow16 = lane & 15, lkh = lane >> 4;

  if constexpr (EPI==EPI_FC2){
    if (tid < 128) tokt[tid] = (int)row2tok(row0 + brow + tid);
    asm volatile("s_waitcnt lgkmcnt(0)" ::: "memory");
  }

  #define STAGE(k0, Ad, Bd) do{ \
    _Pragma("unroll") \
    for (int c = 0; c < 4; c++){ \
      int ch = wid*4 + c; \
      gload16(A + (size_t)(brow + ch*8 + srow)*K + (k0) + sg*8, (Ad) + ch*1024); \
    } \
    _Pragma("unroll") \
    for (int c = 0; c < 2; c++){ \
      int ch = wid*2 + c; \
      gload16(WT + (size_t)(bcol + ch*8 + srow)*K + (k0) + sg*8, (Bd) + ch*1024); \
    } \
  }while(0)

  constexpr int NK = K/64;
  STAGE(0, As[0], Bs[0]);               // prologue
  #pragma unroll
  for (int ki = 0; ki < NK; ki++){
    const int cur = ki & 1;
    if (ki+1 < NK){
      STAGE((ki+1)*64, As[cur^1], Bs[cur^1]);          // prefetch next tile
      asm volatile("s_waitcnt vmcnt(6)" ::: "memory"); // current tile landed
    } else {
      asm volatile("s_waitcnt vmcnt(0)" ::: "memory");
    }
    __builtin_amdgcn_s_barrier();
    __builtin_amdgcn_sched_barrier(0);

    bf16x8 af[4][2], bfr[2][2];
    #pragma unroll
    for (int m=0;m<4;m++)
      #pragma unroll
      for (int ks=0;ks<2;ks++){
        int arow = wm*64 + m*16 + lrow16;
        af[m][ks] = *(const bf16x8*)(As[cur] + arow*128 + (((ks*4+lkh) ^ (arow&7))<<4));
      }
    #pragma unroll
    for (int n=0;n<2;n++)
      #pragma unroll
      for (int ks=0;ks<2;ks++){
        int brn = wn*32 + n*16 + lrow16;
        bfr[n][ks] = *(const bf16x8*)(Bs[cur] + brn*128 + (((ks*4+lkh) ^ (brn&7))<<4));
      }
    #pragma unroll
    for (int m=0;m<4;m++)
      #pragma unroll
      for (int n=0;n<2;n++)
        #pragma unroll
        for (int ks=0;ks<2;ks++)
          acc[m][n] = __builtin_amdgcn_mfma_f32_16x16x32_bf16(
              af[m][ks], bfr[n][ks], acc[m][n], 0, 0, 0);
    if (ki+1 < NK) __builtin_amdgcn_s_barrier();
  }
  #undef STAGE

  float bi[2];
  #pragma unroll
  for (int n=0;n<2;n++) bi[n] = bias[bcol + wn*32 + n*16 + lrow16];
  #pragma unroll
  for (int m=0;m<4;m++){
    #pragma unroll
    for (int j=0;j<4;j++){
      int lr = wm*64 + m*16 + lkh*4 + j;
      int r  = brow + lr;
      if constexpr (EPI==EPI_QKV || EPI==EPI_FC1){
        #pragma unroll
        for (int n=0;n<2;n++){
          float v = acc[m][n][j] + bi[n];
          if constexpr (EPI==EPI_FC1)
            v = fast_gelu(v);
          ((uint16_t*)outp)[(size_t)r*NN + bcol + wn*32 + n*16 + lrow16] = f2bfbits(v);
        }
      } else { // EPI_FC2: token scatter (LDS table) + bf16 residual(x2)
        size_t pr = (size_t)tokt[lr]*CDIM;
        #pragma unroll
        for (int n=0;n<2;n++){
          size_t p = pr + bcol + wn*32 + n*16 + lrow16;
          ((float*)outp)[p] = acc[m][n][j] + bi[n] + bfbits2f(resid[p]);
        }
      }
    }
  }
}

// ----- proj GEMM (64x192 tile, 6 waves, wave 32x64) + fused LN2 ------------
// single-buffered (34.8KB LDS -> 4 blocks/CU): measured optimum (r12/r13).
__global__ __launch_bounds__(384) void proj_ln2(
    const uint16_t* __restrict__ A, const uint16_t* __restrict__ WT,
    const float* __restrict__ pbias, const float* __restrict__ x,
    const float* __restrict__ g2, const float* __restrict__ b2,
    uint16_t* __restrict__ x2out, uint16_t* __restrict__ ln2out, int row0){
  __shared__ __attribute__((aligned(16))) char As[64*128];    // [64][64k]
  __shared__ __attribute__((aligned(16))) char Bs[192*128];   // [192][64k]
  __shared__ float stats[3][64][2];
  __shared__ int tokt[64];
  const int tid  = threadIdx.x;
  const int lane = tid & 63;
  const int wid  = tid >> 6;          // 0..5
  const int pm = wid / 3, pn = wid - pm*3;
  const int brow = blockIdx.x * 64;
  const int srow = lane >> 3;
  const int sg   = (lane & 7) ^ srow;
  const int r16 = lane & 15, t4 = lane >> 4;

  if (tid < 64) tokt[tid] = (int)row2tok(row0 + brow + tid);

  f32x4 acc[2][4];
  #pragma unroll
  for (int m=0;m<2;m++)
    #pragma unroll
    for (int n=0;n<4;n++) acc[m][n] = (f32x4){0.f,0.f,0.f,0.f};

  for (int k0 = 0; k0 < 192; k0 += 64){
    for (int ch = wid; ch < 8; ch += 6)
      gload16(A + (size_t)(brow + ch*8 + srow)*192 + k0 + sg*8, As + ch*1024);
    for (int ch = wid; ch < 24; ch += 6)
      gload16(WT + (size_t)(ch*8 + srow)*192 + k0 + sg*8, Bs + ch*1024);
    __syncthreads();

    bf16x8 af[2][2], bfr[4][2];
    #pragma unroll
    for (int m=0;m<2;m++)
      #pragma unroll
      for (int ks=0;ks<2;ks++){
        int arow = pm*32 + m*16 + r16;
        af[m][ks] = *(const bf16x8*)(As + arow*128 + (((ks*4+t4) ^ (arow&7))<<4));
      }
    #pragma unroll
    for (int n=0;n<4;n++)
      #pragma unroll
      for (int ks=0;ks<2;ks++){
        int brn = pn*64 + n*16 + r16;
        bfr[n][ks] = *(const bf16x8*)(Bs + brn*128 + (((ks*4+t4) ^ (brn&7))<<4));
      }
    #pragma unroll
    for (int m=0;m<2;m++)
      #pragma unroll
      for (int n=0;n<4;n++)
        #pragma unroll
        for (int ks=0;ks<2;ks++)
          acc[m][n] = __builtin_amdgcn_mfma_f32_16x16x32_bf16(
              af[m][ks], bfr[n][ks], acc[m][n], 0, 0, 0);
    __syncthreads();
  }

  float bi[4], g2v[4], b2v[4];
  #pragma unroll
  for (int n=0;n<4;n++){
    int c = pn*64 + n*16 + r16;
    bi[n] = pbias[c]; g2v[n] = g2[c]; b2v[n] = b2[c];
  }
  // pass 1: y = acc + bias + x[token]; write x2 (bf16); per-row partial stats
  #pragma unroll
  for (int m=0;m<2;m++){
    #pragma unroll
    for (int j=0;j<4;j++){
      int lr = pm*32 + m*16 + t4*4 + j;            // local row in [0,64)
      size_t pr = (size_t)tokt[lr]*CDIM;
      float s1 = 0.f, s2 = 0.f;
      #pragma unroll
      for (int n=0;n<4;n++){
        int c = pn*64 + n*16 + r16;
        float y = acc[m][n][j] + bi[n] + x[pr + c];
        acc[m][n][j] = y;
        x2out[pr + c] = f2bfbits(y);
        s1 += y; s2 = fmaf(y, y, s2);
      }
      #pragma unroll
      for (int mk=1; mk<16; mk<<=1){
        s1 += __shfl_xor(s1, mk, 64);
        s2 += __shfl_xor(s2, mk, 64);
      }
      if (r16 == 0){ stats[pn][lr][0] = s1; stats[pn][lr][1] = s2; }
    }
  }
  __syncthreads();
  // pass 2: normalize, write ln2out (window order, block-local rows)
  #pragma unroll
  for (int m=0;m<2;m++){
    #pragma unroll
    for (int j=0;j<4;j++){
      int lr = pm*32 + m*16 + t4*4 + j;
      float s1 = stats[0][lr][0] + stats[1][lr][0] + stats[2][lr][0];
      float s2 = stats[0][lr][1] + stats[1][lr][1] + stats[2][lr][1];
      float mu = s1*(1.f/192.f);
      float rs = rsqrtf(s2*(1.f/192.f) - mu*mu + 1e-5f);
      size_t wr = (size_t)(brow + lr)*CDIM;
      #pragma unroll
      for (int n=0;n<4;n++){
        int c = pn*64 + n*16 + r16;
        ln2out[wr + c] = f2bfbits((acc[m][n][j]-mu)*rs*g2v[n] + b2v[n]);
      }
    }
  }
}

// ------- MFMA windowed attention: 4 window-heads per 256-thread block ------
__global__ __launch_bounds__(256) void attn_kernel(
    const uint16_t* __restrict__ qkv, const float* __restrict__ btbl,
    uint16_t* __restrict__ attnout, int win0){
  const int wv   = threadIdx.x >> 6;
  const int lane = threadIdx.x & 63;
  const int whd  = blockIdx.x*4 + wv;
  const int widx = whd/6, hd = whd - widx*6;
  const int r16 = lane & 15, t4 = lane >> 4;
  __shared__ uint16_t Vt[4][32][72];
  __shared__ uint16_t Pl[4][16][72];

  #pragma unroll
  for (int e=lane; e<32*16; e+=64){ Vt[wv][e>>4][48 + (e&15)] = 0; }
  for (int ch = lane; ch < 196; ch += 64){
    int j = ch >> 2, c0 = (ch&3)*8;
    const uint16_t* src = qkv + ((size_t)widx*49 + j)*576 + hd*32 + 384 + c0;
    uint4 v = *(const uint4*)src;
    uint32_t u[4] = {v.x, v.y, v.z, v.w};
    #pragma unroll
    for (int q=0;q<8;q++) Vt[wv][c0+q][j] = (uint16_t)(u[q>>1] >> ((q&1)*16));
  }

  bf16x8 kf[4];
  #pragma unroll
  for (int jt=0;jt<4;jt++)
    kf[jt] = *(const bf16x8*)(qkv + ((size_t)widx*49 + jt*16 + r16)*576 + hd*32 + 192 + t4*8);

  const int gw = win0 + widx;
  const int cls = ((((gw&1023)>>5)==31)<<1) | ((gw&31)==31);
  const float* tb = btbl + ((size_t)(cls*6 + hd) << 12);
  const float scale = 0.17677669529663689f;

  WFENCE;
  bf16x8 bv[2][2];
  #pragma unroll
  for (int ct=0;ct<2;ct++)
    #pragma unroll
    for (int ks=0;ks<2;ks++)
      bv[ct][ks] = *(const bf16x8*)&Vt[wv][ct*16 + r16][ks*32 + t4*8];

  #pragma unroll 2
  for (int it=0; it<4; it++){
    bf16x8 qf = *(const bf16x8*)(qkv + ((size_t)widx*49 + it*16 + r16)*576 + hd*32 + t4*8);
    f32x4 acc[4];
    #pragma unroll
    for (int jt=0;jt<4;jt++){
      acc[jt] = (f32x4){0.f,0.f,0.f,0.f};
      acc[jt] = __builtin_amdgcn_mfma_f32_16x16x32_bf16(kf[jt], qf, acc[jt], 0,0,0);
    }
    int i = it*16 + r16;
    float s[4][4];
    float m = -3.4e38f;
    #pragma unroll
    for (int jt=0;jt<4;jt++){
      float4 bvv = *(const float4*)(tb + i*64 + jt*16 + t4*4);
      float bb[4] = {bvv.x, bvv.y, bvv.z, bvv.w};
      #pragma unroll
      for (int r=0;r<4;r++){
        s[jt][r] = acc[jt][r]*scale + bb[r];
        m = fmaxf(m, s[jt][r]);
      }
    }
    m = fmaxf(m, __shfl_xor(m, 16, 64));
    m = fmaxf(m, __shfl_xor(m, 32, 64));
    float sum = 0.f;
    #pragma unroll
    for (int jt=0;jt<4;jt++)
      #pragma unroll
      for (int r=0;r<4;r++){
        s[jt][r] = __expf(s[jt][r] - m);
        sum += s[jt][r];
      }
    sum += __shfl_xor(sum, 16, 64);
    sum += __shfl_xor(sum, 32, 64);
    float inv = 1.f / sum;
    #pragma unroll
    for (int jt=0;jt<4;jt++){
      uint32_t lo = (uint32_t)f2bfbits(s[jt][0]*inv) | ((uint32_t)f2bfbits(s[jt][1]*inv) << 16);
      uint32_t hi = (uint32_t)f2bfbits(s[jt][2]*inv) | ((uint32_t)f2bfbits(s[jt][3]*inv) << 16);
      *(uint2*)&Pl[wv][r16][jt*16 + t4*4] = make_uint2(lo, hi);
    }
    asm volatile("s_waitcnt lgkmcnt(0)" ::: "memory");

    f32x4 o[2];
    o[0] = (f32x4){0.f,0.f,0.f,0.f};
    o[1] = (f32x4){0.f,0.f,0.f,0.f};
    #pragma unroll
    for (int ks=0;ks<2;ks++){
      bf16x8 pa = *(const bf16x8*)&Pl[wv][r16][ks*32 + t4*8];
      #pragma unroll
      for (int ct=0;ct<2;ct++)
        o[ct] = __builtin_amdgcn_mfma_f32_16x16x32_bf16(pa, bv[ct][ks], o[ct], 0,0,0);
    }
    #pragma unroll
    for (int r=0;r<4;r++){
      int i2 = it*16 + t4*4 + r;
      if (i2 < 49){
        size_t base = ((size_t)widx*49 + i2)*CDIM + hd*32;
        attnout[base + r16]      = f2bfbits(o[0][r]);
        attnout[base + 16 + r16] = f2bfbits(o[1][r]);
      }
    }
  }
}

// ---------------------------------------------------------------------------
extern "C" void kernel_launch(void* const* d_in, const int* in_sizes, int n_in,
                              void* d_out, int out_size, void* d_ws, size_t ws_size,
                              hipStream_t stream) {
  const float* x       = (const float*)d_in[0];
  const float* n1g     = (const float*)d_in[1];
  const float* n1b     = (const float*)d_in[2];
  const float* qkv_w   = (const float*)d_in[3];
  const float* qkv_b   = (const float*)d_in[4];
  const float* rpb     = (const float*)d_in[5];
  const float* proj_w  = (const float*)d_in[6];
  const float* proj_b  = (const float*)d_in[7];
  const float* n2g     = (const float*)d_in[8];
  const float* n2b     = (const float*)d_in[9];
  const float* fc1_w   = (const float*)d_in[10];
  const float* fc1_b   = (const float*)d_in[11];
  const float* fc2_w   = (const float*)d_in[12];
  const float* fc2_b   = (const float*)d_in[13];
  float* out = (float*)d_out;

  const int T = 200704;
  const size_t TBL = 221184 + 73728 + 294912 + 294912 + 393216;
  const size_t ABYTES = (size_t)T*CDIM*2;       // 77.1 MB (Abuf / X2 each)
  const size_t BQFULL = (size_t)T*768*2;        // 308.3 MB (full qkv / hid)
  size_t need_full = ABYTES + BQFULL + ABYTES + TBL;   // ~464 MB
  bool full = ws_size >= need_full;

  char* ws = (char*)d_ws;
  if (full){
    uint16_t* Abuf = (uint16_t*)ws;                      // window-order stage
    uint16_t* Bq   = (uint16_t*)(ws + ABYTES);           // full qkv / hid
    uint16_t* X2   = (uint16_t*)(ws + ABYTES + BQFULL);  // x2 bf16 (token order)
    char* wbase    = ws + ABYTES + BQFULL + ABYTES;
    uint16_t* qkvW = (uint16_t*)wbase;
    uint16_t* prjW = (uint16_t*)(wbase + 221184);
    uint16_t* fc1W = (uint16_t*)(wbase + 221184 + 73728);
    uint16_t* fc2W = (uint16_t*)(wbase + 221184 + 73728 + 294912);
    float*    btbl = (float*)(wbase + 221184 + 73728 + 294912 + 294912);

    prep_kernel<<<2112, 256, 0, stream>>>(qkv_w, proj_w, fc1_w, fc2_w, rpb,
                                          qkvW, prjW, fc1W, fc2W, btbl);
    ln1_kernel<<<T/4, 256, 0, stream>>>(x, n1g, n1b, Abuf, 0);
    mgemm<EPI_QKV, 192, 576>
        <<<dim3(9, T/128), 256, 0, stream>>>(Abuf, qkvW, qkv_b, (void*)Bq, nullptr, 0);
    attn_kernel<<<(T/49)*6/4, 256, 0, stream>>>(Bq, btbl, Abuf, 0);
    proj_ln2<<<T/64, 384, 0, stream>>>(Abuf, prjW, proj_b, x, n2g, n2b,
                                       X2, Abuf, 0);
    mgemm<EPI_FC1, 192, 768>
        <<<dim3(12, T/128), 256, 0, stream>>>(Abuf, fc1W, fc1_b, (void*)Bq, nullptr, 0);
    mgemm<EPI_FC2, 768, 192>
        <<<dim3(3, T/128), 256, 0, stream>>>(Bq, fc2W, fc2_b, (void*)out, X2, 0);
  } else {
    // fallback: per-batch-image chunks (needs ~175MB)
    const int TC = MB, NW = TC/49;
    uint16_t* Abuf = (uint16_t*)ws;
    uint16_t* Bq   = (uint16_t*)(ws + (size_t)TC*CDIM*2);
    uint16_t* X2   = (uint16_t*)(ws + (size_t)TC*CDIM*2 + (size_t)TC*768*2);
    char* wbase    = ws + (size_t)TC*CDIM*2 + (size_t)TC*768*2 + ABYTES;
    uint16_t* qkvW = (uint16_t*)wbase;
    uint16_t* prjW = (uint16_t*)(wbase + 221184);
    uint16_t* fc1W = (uint16_t*)(wbase + 221184 + 73728);
    uint16_t* fc2W = (uint16_t*)(wbase + 221184 + 73728 + 294912);
    float*    btbl = (float*)(wbase + 221184 + 73728 + 294912 + 294912);

    prep_kernel<<<2112, 256, 0, stream>>>(qkv_w, proj_w, fc1_w, fc2_w, rpb,
                                          qkvW, prjW, fc1W, fc2W, btbl);
    for (int c = 0; c < 4; c++){
      int row0 = c*TC, win0 = row0/49;
      ln1_kernel<<<TC/4, 256, 0, stream>>>(x, n1g, n1b, Abuf, row0);
      mgemm<EPI_QKV, 192, 576>
          <<<dim3(9, TC/128), 256, 0, stream>>>(Abuf, qkvW, qkv_b, (void*)Bq, nullptr, 0);
      attn_kernel<<<NW*6/4, 256, 0, stream>>>(Bq, btbl, Abuf, win0);
      proj_ln2<<<TC/64, 384, 0, stream>>>(Abuf, prjW, proj_b, x, n2g, n2b,
                                          X2, Abuf, row0);
      mgemm<EPI_FC1, 192, 768>
          <<<dim3(12, TC/128), 256, 0, stream>>>(Abuf, fc1W, fc1_b, (void*)Bq, nullptr, 0);
      mgemm<EPI_FC2, 768, 192>
          <<<dim3(3, TC/128), 256, 0, stream>>>(Bq, fc2W, fc2_b, (void*)out, X2, row0);
    }
  }
}